// Round 4
// baseline (658.548 us; speedup 1.0000x reference)
//
#include <hip/hip_runtime.h>
#include <math.h>
#include <stdint.h>

#define S_LEN 2048
#define B_N 16
#define C_DIM 1024
#define H_DIM 1024
#define T_OUT 512
#define NROWS (S_LEN * B_N) /* 32768 */
#define PT 4                /* partial tiles: H / 256 */
#define NT 48               /* K' = 3*1024 / 64 */

typedef __attribute__((ext_vector_type(8))) short short8_t;
typedef __attribute__((ext_vector_type(4))) float f32x4;

__device__ __forceinline__ unsigned short f2bf_rne(float f) {
  unsigned u = __float_as_uint(f);
  u += 0x7FFF + ((u >> 16) & 1);
  return (unsigned short)(u >> 16);
}
__device__ __forceinline__ float bf2f(unsigned short h) {
  return __uint_as_float(((unsigned)h) << 16);
}
__device__ __forceinline__ unsigned pack2(unsigned short a, unsigned short b) {
  return (unsigned)a | ((unsigned)b << 16);
}
__device__ __forceinline__ void gload_lds16(const void* g, void* l) {
  __builtin_amdgcn_global_load_lds((const __attribute__((address_space(1))) unsigned*)g,
                                   (__attribute__((address_space(3))) unsigned*)l, 16, 0, 0);
}
__device__ __forceinline__ void split8(const float* f, uint4& hv, uint4& lv) {
  unsigned short hi[8], lo[8];
#pragma unroll
  for (int i = 0; i < 8; ++i) {
    hi[i] = f2bf_rne(f[i]);
    lo[i] = f2bf_rne(f[i] - bf2f(hi[i]));
  }
  hv.x = pack2(hi[0], hi[1]); hv.y = pack2(hi[2], hi[3]);
  hv.z = pack2(hi[4], hi[5]); hv.w = pack2(hi[6], hi[7]);
  lv.x = pack2(lo[0], lo[1]); lv.y = pack2(lo[2], lo[3]);
  lv.z = pack2(lo[4], lo[5]); lv.w = pack2(lo[6], lo[7]);
}
__device__ __forceinline__ float tanh_fast(float v) {
  // 1 - 2/(e^{2v}+1); stable at both tails (exp->inf gives 1, exp->0 gives -1)
  return 1.f - 2.f / (__expf(2.f * v) + 1.f);
}

// ---------------- w2 = g2 * v2 / ||v2|| ----------------
__global__ __launch_bounds__(256) void w2_kernel(const float* __restrict__ v2,
                                                 const float* __restrict__ g2,
                                                 float* __restrict__ w2) {
  __shared__ float red[256];
  int tid = threadIdx.x;
  float s = 0.f;
  for (int h = tid; h < H_DIM; h += 256) { float v = v2[h]; s += v * v; }
  red[tid] = s;
  __syncthreads();
  for (int off = 128; off > 0; off >>= 1) {
    if (tid < off) red[tid] += red[tid + off];
    __syncthreads();
  }
  float scale = g2[0] / sqrtf(red[0]);
  for (int h = tid; h < H_DIM; h += 256) w2[h] = v2[h] * scale;
}

// ---------------- x -> x_hi, x_lo (bf16 split, once per element) ----------------
__global__ __launch_bounds__(256) void cvt_x_kernel(const float* __restrict__ x,
                                                    uint16_t* __restrict__ x_hi,
                                                    uint16_t* __restrict__ x_lo) {
  const size_t nchunks = (size_t)NROWS * C_DIM / 8;
  const size_t stride = (size_t)gridDim.x * blockDim.x;
  for (size_t i = (size_t)blockIdx.x * blockDim.x + threadIdx.x; i < nchunks; i += stride) {
    float4 v0 = *(const float4*)(x + i * 8);
    float4 v1 = *(const float4*)(x + i * 8 + 4);
    float f[8] = {v0.x, v0.y, v0.z, v0.w, v1.x, v1.y, v1.z, v1.w};
    uint4 hv, lv;
    split8(f, hv, lv);
    *(uint4*)(x_hi + i * 8) = hv;
    *(uint4*)(x_lo + i * 8) = lv;
  }
}

// ---------------- w1[c][h] -> w_hiT[h][c], w_loT[h][c] ----------------
__global__ __launch_bounds__(256) void cvt_w_kernel(const float* __restrict__ w1,
                                                    uint16_t* __restrict__ w_hiT,
                                                    uint16_t* __restrict__ w_loT) {
  __shared__ unsigned short hi_t[64][65], lo_t[64][65];
  const int h0 = blockIdx.x * 64, c0 = blockIdx.y * 64;
  const int tid = threadIdx.x;
  const int cl = tid >> 4;
  const int hl = (tid & 15) * 4;
#pragma unroll
  for (int k = 0; k < 4; ++k) {
    int c = cl + k * 16;
    float4 v = *(const float4*)(w1 + (size_t)(c0 + c) * H_DIM + h0 + hl);
    float f[4] = {v.x, v.y, v.z, v.w};
#pragma unroll
    for (int i = 0; i < 4; ++i) {
      unsigned short hi = f2bf_rne(f[i]);
      unsigned short lo = f2bf_rne(f[i] - bf2f(hi));
      hi_t[c][hl + i] = hi;
      lo_t[c][hl + i] = lo;
    }
  }
  __syncthreads();
  const int hr = tid >> 2;
  const int cc = (tid & 3) * 16;
  uint4 o[4];
#pragma unroll
  for (int g = 0; g < 2; ++g) {
    unsigned short (*src)[65] = g ? lo_t : hi_t;
    o[g * 2 + 0].x = pack2(src[cc + 0][hr], src[cc + 1][hr]);
    o[g * 2 + 0].y = pack2(src[cc + 2][hr], src[cc + 3][hr]);
    o[g * 2 + 0].z = pack2(src[cc + 4][hr], src[cc + 5][hr]);
    o[g * 2 + 0].w = pack2(src[cc + 6][hr], src[cc + 7][hr]);
    o[g * 2 + 1].x = pack2(src[cc + 8][hr], src[cc + 9][hr]);
    o[g * 2 + 1].y = pack2(src[cc + 10][hr], src[cc + 11][hr]);
    o[g * 2 + 1].z = pack2(src[cc + 12][hr], src[cc + 13][hr]);
    o[g * 2 + 1].w = pack2(src[cc + 14][hr], src[cc + 15][hr]);
  }
  uint16_t* ph = w_hiT + (size_t)(h0 + hr) * C_DIM + c0 + cc;
  uint16_t* pl = w_loT + (size_t)(h0 + hr) * C_DIM + c0 + cc;
  *(uint4*)ph = o[0]; *(uint4*)(ph + 8) = o[1];
  *(uint4*)pl = o[2]; *(uint4*)(pl + 8) = o[3];
}

// ---------------- 256x256x(K'=3072) 8-phase-family bf16 GEMM + tanh/w2 epilogue -------
// LDS per tile row (64 bf16 = 8 x 16B slots): phys slot p at row r holds logical
// slot p ^ (r&7).  Staging pre-swizzles the GLOBAL source address (rule #21);
// ds_read applies the same XOR.  4 phases per K-tile; quarter-stages of tile t+1
// issued 2/phase in order [B0,B1,B2,B3,A0,A1,A2,A3]; counted vmcnt per phase
// (steady {1,3,4,6}) keeps loads in flight across barriers (T4).
template <int P, bool STG, int VM>
__device__ __forceinline__ void phase_body(
    const uint16_t* Ac, const uint16_t* Bc,
    const uint16_t* asrc, const uint16_t* bsrc,
    uint16_t* An, uint16_t* Bn,
    f32x4 (&acc)[8][4], short8_t (&bF)[4][2],
    int wm, int wn, int l15, int lk, int ldst) {
  asm volatile("s_waitcnt vmcnt(%0)" :: "n"(VM) : "memory");
  __builtin_amdgcn_s_barrier();
  __builtin_amdgcn_sched_barrier(0);
  const int sw = l15 & 7;
  const int r0 = wm * 128 + (2 * P) * 16 + l15;
  const int r1 = r0 + 16;
  short8_t a00 = *(const short8_t*)(Ac + r0 * 64 + ((lk ^ sw) * 8));
  short8_t a01 = *(const short8_t*)(Ac + r0 * 64 + (((4 + lk) ^ sw) * 8));
  short8_t a10 = *(const short8_t*)(Ac + r1 * 64 + ((lk ^ sw) * 8));
  short8_t a11 = *(const short8_t*)(Ac + r1 * 64 + (((4 + lk) ^ sw) * 8));
  if (P == 0) {
#pragma unroll
    for (int nf = 0; nf < 4; ++nf) {
      const int rb = wn * 64 + nf * 16 + l15;  // rb&7 == sw
      bF[nf][0] = *(const short8_t*)(Bc + rb * 64 + ((lk ^ sw) * 8));
      bF[nf][1] = *(const short8_t*)(Bc + rb * 64 + (((4 + lk) ^ sw) * 8));
    }
  }
  if (STG) {
    if (P == 0) {
      gload_lds16(bsrc, Bn + ldst);
      gload_lds16(bsrc + 65536, Bn + 4096 + ldst);
    } else if (P == 1) {
      gload_lds16(bsrc + 2 * 65536, Bn + 2 * 4096 + ldst);
      gload_lds16(bsrc + 3 * 65536, Bn + 3 * 4096 + ldst);
    } else if (P == 2) {
      gload_lds16(asrc, An + ldst);
      gload_lds16(asrc + 65536, An + 4096 + ldst);
    } else {
      gload_lds16(asrc + 2 * 65536, An + 2 * 4096 + ldst);
      gload_lds16(asrc + 3 * 65536, An + 3 * 4096 + ldst);
    }
  }
  __builtin_amdgcn_s_setprio(1);
#pragma unroll
  for (int nf = 0; nf < 4; ++nf) {
    acc[2 * P][nf] = __builtin_amdgcn_mfma_f32_16x16x32_bf16(a00, bF[nf][0], acc[2 * P][nf], 0, 0, 0);
    acc[2 * P][nf] = __builtin_amdgcn_mfma_f32_16x16x32_bf16(a01, bF[nf][1], acc[2 * P][nf], 0, 0, 0);
    acc[2 * P + 1][nf] = __builtin_amdgcn_mfma_f32_16x16x32_bf16(a10, bF[nf][0], acc[2 * P + 1][nf], 0, 0, 0);
    acc[2 * P + 1][nf] = __builtin_amdgcn_mfma_f32_16x16x32_bf16(a11, bF[nf][1], acc[2 * P + 1][nf], 0, 0, 0);
  }
  __builtin_amdgcn_s_setprio(0);
}

__global__ __launch_bounds__(512, 2) void gemm_alpha_8p(
    const uint16_t* __restrict__ x_hi, const uint16_t* __restrict__ x_lo,
    const uint16_t* __restrict__ w_hiT, const uint16_t* __restrict__ w_loT,
    const float* __restrict__ b1, const float* __restrict__ w2,
    float* __restrict__ partial) {
  __shared__ uint16_t S[65536];  // 128 KiB: A0 @0, A1 @16384, B0 @32768, B1 @49152

  // XCD-aware mapping: each XCD gets 16 row-panels; 4 col-tiles of a row adjacent
  const int hw = blockIdx.x;
  const int slot = hw >> 3;
  const int rt = (hw & 7) * 16 + (slot >> 2);
  const int ct = slot & 3;
  const int rs0 = rt * 256;
  const int h0 = ct * 256;

  const int tid = threadIdx.x;
  const int lane = tid & 63;
  const int w = tid >> 6;
  const int wm = w >> 2, wn = w & 3;
  const int l15 = lane & 15, lk = lane >> 4;

  // staging per-thread geometry: one gload_lds16 per wave covers 8 rows x 128B
  const int srow = w * 8 + (lane >> 3);
  const int slotx = ((lane & 7) ^ ((lane >> 3) & 7)) * 8;  // pre-swizzled source col
  const size_t aoff = (size_t)(rs0 + srow) * C_DIM + slotx;
  const size_t boff = (size_t)(h0 + srow) * C_DIM + slotx;
  const int ldst = w * 512;  // wave-uniform elem offset within a quarter slab

  f32x4 acc[8][4];
#pragma unroll
  for (int i = 0; i < 8; ++i)
#pragma unroll
    for (int j = 0; j < 4; ++j) acc[i][j] = (f32x4){0.f, 0.f, 0.f, 0.f};
  short8_t bF[4][2];

  // prologue: stage tile 0 into buf 0, order B0..B3, A0..A3
  {
    const uint16_t* b0 = w_hiT + boff;
    const uint16_t* a0 = x_hi + aoff;
#pragma unroll
    for (int q = 0; q < 4; ++q) gload_lds16(b0 + q * 65536, S + 32768 + q * 4096 + ldst);
#pragma unroll
    for (int q = 0; q < 4; ++q) gload_lds16(a0 + q * 65536, S + q * 4096 + ldst);
  }

#pragma unroll 2
  for (int t = 0; t < NT; ++t) {
    const int c = t & 1;
    const uint16_t* Ac = S + c * 16384;
    const uint16_t* Bc = S + 32768 + c * 16384;
    uint16_t* An = S + (1 - c) * 16384;
    uint16_t* Bn = S + 32768 + (1 - c) * 16384;
    const int t1 = t + 1;
    const int th1 = t1 >> 4;  // K' third: 0=hi*hi 1=lo*hi 2=hi*lo
    const uint16_t* asrc = ((th1 == 1) ? x_lo : x_hi) + aoff + (size_t)(t1 & 15) * 64;
    const uint16_t* bsrc = ((th1 == 2) ? w_loT : w_hiT) + boff + (size_t)(t1 & 15) * 64;
    if (t1 < NT) {
      phase_body<0, true, 1>(Ac, Bc, asrc, bsrc, An, Bn, acc, bF, wm, wn, l15, lk, ldst);
      phase_body<1, true, 3>(Ac, Bc, asrc, bsrc, An, Bn, acc, bF, wm, wn, l15, lk, ldst);
      phase_body<2, true, 4>(Ac, Bc, asrc, bsrc, An, Bn, acc, bF, wm, wn, l15, lk, ldst);
      phase_body<3, true, 6>(Ac, Bc, asrc, bsrc, An, Bn, acc, bF, wm, wn, l15, lk, ldst);
    } else {
      phase_body<0, false, 1>(Ac, Bc, asrc, bsrc, An, Bn, acc, bF, wm, wn, l15, lk, ldst);
      phase_body<1, false, 1>(Ac, Bc, asrc, bsrc, An, Bn, acc, bF, wm, wn, l15, lk, ldst);
      phase_body<2, false, 0>(Ac, Bc, asrc, bsrc, An, Bn, acc, bF, wm, wn, l15, lk, ldst);
      phase_body<3, false, 0>(Ac, Bc, asrc, bsrc, An, Bn, acc, bF, wm, wn, l15, lk, ldst);
    }
  }

  // ---- epilogue: tanh + dot(w2) -> per-row partial ----
  __syncthreads();
  float* red = (float*)S;  // [256][65] = 66.5 KB
  float bv[4], wv[4];
#pragma unroll
  for (int nf = 0; nf < 4; ++nf) {
    const int h = h0 + wn * 64 + nf * 16 + l15;
    bv[nf] = b1[h];
    wv[nf] = w2[h];
  }
#pragma unroll
  for (int mf = 0; mf < 8; ++mf)
#pragma unroll
    for (int r = 0; r < 4; ++r) {
      float s = 0.f;
#pragma unroll
      for (int nf = 0; nf < 4; ++nf) s += tanh_fast(acc[mf][nf][r] + bv[nf]) * wv[nf];
      const int row = wm * 128 + mf * 16 + lk * 4 + r;
      red[row * 65 + wn * 16 + l15] = s;
    }
  __syncthreads();
  if (tid < 256) {
    float s = 0.f;
#pragma unroll
    for (int i = 0; i < 64; ++i) s += red[tid * 65 + i];
    partial[(size_t)ct * NROWS + rs0 + tid] = s;
  }
}

// ---------------- per-batch: alpha, alpha_sum, scale, cumsum, right_idx ----------------
__global__ __launch_bounds__(256) void scan_kernel(
    const float* __restrict__ partial, const int* __restrict__ tlen,
    const float* __restrict__ b2p,
    float* __restrict__ alpha_s, float* __restrict__ csum,
    int* __restrict__ ridx, float* __restrict__ tail) {
  const int b = blockIdx.x;
  const int tid = threadIdx.x;
  const float b2 = b2p[0];
  float a[8];
  float lsum = 0.f;
#pragma unroll
  for (int i = 0; i < 8; ++i) {
    int s = tid * 8 + i;
    float lg = b2;
#pragma unroll
    for (int t = 0; t < PT; ++t) lg += partial[t * NROWS + s * B_N + b];
    float al = 1.f / (1.f + expf(-lg));
    a[i] = al;
    lsum += al;
  }
  __shared__ float tsum[256];
  tsum[tid] = lsum;
  __syncthreads();
  for (int off = 1; off < 256; off <<= 1) {
    float v = 0.f;
    if (tid >= off) v = tsum[tid - off];
    __syncthreads();
    tsum[tid] += v;
    __syncthreads();
  }
  float total = tsum[255];
  float pre = tid ? tsum[tid - 1] : 0.f;
  float desired = (float)tlen[b] + 0.0001f; // BETA = 1
  float scale = desired / total;
  float run = pre;
#pragma unroll
  for (int i = 0; i < 8; ++i) {
    int s = tid * 8 + i;
    run += a[i];
    float cs = run * scale;
    int r = (int)floorf(cs);
    r = r < 0 ? 0 : (r > T_OUT ? T_OUT : r);
    alpha_s[b * S_LEN + s] = a[i] * scale;
    csum[b * S_LEN + s] = cs;
    ridx[b * S_LEN + s] = r;
  }
  if (tid == 0) {
    tail[b] = (float)tlen[b];       // feat_lengths (compared as float)
    tail[B_N + b] = total;          // alpha_sum (pre-scaling)
  }
}

// ---------------- per-(frame, batch): gather the contiguous s-band ----------------
__global__ __launch_bounds__(256) void frames_kernel(
    const float* __restrict__ x, const float* __restrict__ alpha_s,
    const float* __restrict__ csum, const int* __restrict__ ridx,
    float* __restrict__ out) {
  const int j = blockIdx.x;
  const int b = blockIdx.y;
  const int* r = ridx + b * S_LEN;
  const float* cs = csum + b * S_LEN;
  const float* as = alpha_s + b * S_LEN;

  int lo = 0, hi = S_LEN;
  while (lo < hi) { int m = (lo + hi) >> 1; if (r[m] < j) lo = m + 1; else hi = m; }
  const int sA = lo;
  hi = S_LEN;
  while (lo < hi) { int m = (lo + hi) >> 1; if (r[m] < j + 1) lo = m + 1; else hi = m; }
  int sEnd = lo;
  if (sEnd > S_LEN - 1) sEnd = S_LEN - 1;

  const int tid = threadIdx.x;
  float4 acc = make_float4(0.f, 0.f, 0.f, 0.f);
  for (int s = sA; s <= sEnd; ++s) {
    const int rr = r[s];
    const int l = s ? r[s - 1] : 0;
    float w = 0.f;
    if (rr == l) {
      if (j == rr) w = as[s];
    } else {
      float rw = cs[s] - (float)rr;
      if (j == rr) w = rw;
      else if (j == l) w = as[s] - rw - (float)(rr - l - 1);
      else w = 1.0f;
    }
    if (w != 0.f) {
      const float4 xv = *(const float4*)(x + ((size_t)s * B_N + b) * C_DIM + tid * 4);
      acc.x += w * xv.x; acc.y += w * xv.y; acc.z += w * xv.z; acc.w += w * xv.w;
    }
  }
  *(float4*)(out + ((size_t)j * B_N + b) * C_DIM + tid * 4) = acc;
}

extern "C" void kernel_launch(void* const* d_in, const int* in_sizes, int n_in,
                              void* d_out, int out_size, void* d_ws, size_t ws_size,
                              hipStream_t stream) {
  const float* x = (const float*)d_in[0];
  const int* tlen = (const int*)d_in[2];
  const float* w1 = (const float*)d_in[3];
  const float* b1 = (const float*)d_in[4];
  const float* v2 = (const float*)d_in[5];
  const float* g2 = (const float*)d_in[6];
  const float* b2 = (const float*)d_in[7];
  float* out = (float*)d_out;

  char* ws = (char*)d_ws;
  float* partial = (float*)ws;                          ws += sizeof(float) * PT * NROWS;
  float* alpha_s = (float*)ws;                          ws += sizeof(float) * NROWS;
  float* csum = (float*)ws;                             ws += sizeof(float) * NROWS;
  float* w2 = (float*)ws;                               ws += sizeof(float) * H_DIM;
  int* ridx = (int*)ws;                                 ws += sizeof(int) * NROWS;
  uint16_t* w_hiT = (uint16_t*)ws;                      ws += sizeof(uint16_t) * H_DIM * C_DIM;
  uint16_t* w_loT = (uint16_t*)ws;                      ws += sizeof(uint16_t) * H_DIM * C_DIM;
  uint16_t* x_hi = (uint16_t*)ws;                       ws += sizeof(uint16_t) * (size_t)NROWS * C_DIM;
  uint16_t* x_lo = (uint16_t*)ws;                       ws += sizeof(uint16_t) * (size_t)NROWS * C_DIM;

  w2_kernel<<<dim3(1), dim3(256), 0, stream>>>(v2, g2, w2);
  cvt_w_kernel<<<dim3(16, 16), dim3(256), 0, stream>>>(w1, w_hiT, w_loT);
  cvt_x_kernel<<<dim3(4096), dim3(256), 0, stream>>>(x, x_hi, x_lo);
  gemm_alpha_8p<<<dim3(512), dim3(512), 0, stream>>>(x_hi, x_lo, w_hiT, w_loT, b1, w2, partial);
  scan_kernel<<<dim3(B_N), dim3(256), 0, stream>>>(partial, tlen, b2, alpha_s, csum, ridx,
                                                   out + (size_t)T_OUT * B_N * C_DIM);
  frames_kernel<<<dim3(T_OUT, B_N), dim3(256), 0, stream>>>(x, alpha_s, csum, ridx, out);
}

// Round 5
// 652.125 us; speedup vs baseline: 1.0098x; 1.0098x over previous
//
#include <hip/hip_runtime.h>
#include <math.h>
#include <stdint.h>

#define S_LEN 2048
#define B_N 16
#define C_DIM 1024
#define H_DIM 1024
#define T_OUT 512
#define NROWS (S_LEN * B_N) /* 32768 */
#define PT 4                /* partial tiles: H / 256 */
#define NT 48               /* K' = 3*1024 / 64 */

typedef __attribute__((ext_vector_type(8))) short short8_t;
typedef __attribute__((ext_vector_type(4))) float f32x4;

__device__ __forceinline__ unsigned short f2bf_rne(float f) {
  unsigned u = __float_as_uint(f);
  u += 0x7FFF + ((u >> 16) & 1);
  return (unsigned short)(u >> 16);
}
__device__ __forceinline__ float bf2f(unsigned short h) {
  return __uint_as_float(((unsigned)h) << 16);
}
__device__ __forceinline__ unsigned pack2(unsigned short a, unsigned short b) {
  return (unsigned)a | ((unsigned)b << 16);
}
__device__ __forceinline__ void gload_lds16(const void* g, void* l) {
  __builtin_amdgcn_global_load_lds((const __attribute__((address_space(1))) unsigned*)g,
                                   (__attribute__((address_space(3))) unsigned*)l, 16, 0, 0);
}
__device__ __forceinline__ void split8(const float* f, uint4& hv, uint4& lv) {
  unsigned short hi[8], lo[8];
#pragma unroll
  for (int i = 0; i < 8; ++i) {
    hi[i] = f2bf_rne(f[i]);
    lo[i] = f2bf_rne(f[i] - bf2f(hi[i]));
  }
  hv.x = pack2(hi[0], hi[1]); hv.y = pack2(hi[2], hi[3]);
  hv.z = pack2(hi[4], hi[5]); hv.w = pack2(hi[6], hi[7]);
  lv.x = pack2(lo[0], lo[1]); lv.y = pack2(lo[2], lo[3]);
  lv.z = pack2(lo[4], lo[5]); lv.w = pack2(lo[6], lo[7]);
}
__device__ __forceinline__ float tanh_fast(float v) {
  return 1.f - 2.f / (__expf(2.f * v) + 1.f);
}

// ---------------- w2 = g2 * v2 / ||v2|| ----------------
__global__ __launch_bounds__(256) void w2_kernel(const float* __restrict__ v2,
                                                 const float* __restrict__ g2,
                                                 float* __restrict__ w2) {
  __shared__ float red[256];
  int tid = threadIdx.x;
  float s = 0.f;
  for (int h = tid; h < H_DIM; h += 256) { float v = v2[h]; s += v * v; }
  red[tid] = s;
  __syncthreads();
  for (int off = 128; off > 0; off >>= 1) {
    if (tid < off) red[tid] += red[tid + off];
    __syncthreads();
  }
  float scale = g2[0] / sqrtf(red[0]);
  for (int h = tid; h < H_DIM; h += 256) w2[h] = v2[h] * scale;
}

// ---------------- x -> x_hi, x_lo (bf16 split, once per element) ----------------
__global__ __launch_bounds__(256) void cvt_x_kernel(const float* __restrict__ x,
                                                    uint16_t* __restrict__ x_hi,
                                                    uint16_t* __restrict__ x_lo) {
  const size_t nchunks = (size_t)NROWS * C_DIM / 8;
  const size_t stride = (size_t)gridDim.x * blockDim.x;
  for (size_t i = (size_t)blockIdx.x * blockDim.x + threadIdx.x; i < nchunks; i += stride) {
    float4 v0 = *(const float4*)(x + i * 8);
    float4 v1 = *(const float4*)(x + i * 8 + 4);
    float f[8] = {v0.x, v0.y, v0.z, v0.w, v1.x, v1.y, v1.z, v1.w};
    uint4 hv, lv;
    split8(f, hv, lv);
    *(uint4*)(x_hi + i * 8) = hv;
    *(uint4*)(x_lo + i * 8) = lv;
  }
}

// ---------------- w1[c][h] -> w_hiT[h][c], w_loT[h][c] ----------------
__global__ __launch_bounds__(256) void cvt_w_kernel(const float* __restrict__ w1,
                                                    uint16_t* __restrict__ w_hiT,
                                                    uint16_t* __restrict__ w_loT) {
  __shared__ unsigned short hi_t[64][65], lo_t[64][65];
  const int h0 = blockIdx.x * 64, c0 = blockIdx.y * 64;
  const int tid = threadIdx.x;
  const int cl = tid >> 4;
  const int hl = (tid & 15) * 4;
#pragma unroll
  for (int k = 0; k < 4; ++k) {
    int c = cl + k * 16;
    float4 v = *(const float4*)(w1 + (size_t)(c0 + c) * H_DIM + h0 + hl);
    float f[4] = {v.x, v.y, v.z, v.w};
#pragma unroll
    for (int i = 0; i < 4; ++i) {
      unsigned short hi = f2bf_rne(f[i]);
      unsigned short lo = f2bf_rne(f[i] - bf2f(hi));
      hi_t[c][hl + i] = hi;
      lo_t[c][hl + i] = lo;
    }
  }
  __syncthreads();
  const int hr = tid >> 2;
  const int cc = (tid & 3) * 16;
  uint4 o[4];
#pragma unroll
  for (int g = 0; g < 2; ++g) {
    unsigned short (*src)[65] = g ? lo_t : hi_t;
    o[g * 2 + 0].x = pack2(src[cc + 0][hr], src[cc + 1][hr]);
    o[g * 2 + 0].y = pack2(src[cc + 2][hr], src[cc + 3][hr]);
    o[g * 2 + 0].z = pack2(src[cc + 4][hr], src[cc + 5][hr]);
    o[g * 2 + 0].w = pack2(src[cc + 6][hr], src[cc + 7][hr]);
    o[g * 2 + 1].x = pack2(src[cc + 8][hr], src[cc + 9][hr]);
    o[g * 2 + 1].y = pack2(src[cc + 10][hr], src[cc + 11][hr]);
    o[g * 2 + 1].z = pack2(src[cc + 12][hr], src[cc + 13][hr]);
    o[g * 2 + 1].w = pack2(src[cc + 14][hr], src[cc + 15][hr]);
  }
  uint16_t* ph = w_hiT + (size_t)(h0 + hr) * C_DIM + c0 + cc;
  uint16_t* pl = w_loT + (size_t)(h0 + hr) * C_DIM + c0 + cc;
  *(uint4*)ph = o[0]; *(uint4*)(ph + 8) = o[1];
  *(uint4*)pl = o[2]; *(uint4*)(pl + 8) = o[3];
}

// ---------------- 256x256x(K'=3072) 8-phase-family bf16 GEMM + tanh/w2 epilogue -------
// LDS per tile row (64 bf16 = 8 x 16B slots): phys slot p at row r holds logical
// slot p ^ (r&7).  Staging pre-swizzles the GLOBAL source address (rule #21);
// ds_read applies the same XOR.  4 phases per K-tile; quarter-stages of tile t+1
// issued 2/phase in order [B0,B1,B2,B3,A0,A1,A2,A3]; counted vmcnt per phase
// (steady {1,3,4,6}) keeps loads in flight across barriers (T4).
// Per-wave vmcnt is sound: each wave contributes 8 rows to EVERY quarter-slab and
// publishes them via its own vmcnt before its barrier arrival.
template <int P, bool STG, int VM>
__device__ __forceinline__ void phase_body(
    const uint16_t* Ac, const uint16_t* Bc,
    const uint16_t* asrc, const uint16_t* bsrc,
    uint16_t* An, uint16_t* Bn,
    f32x4 (&acc)[8][4], short8_t (&bF)[4][2],
    int wm, int wn, int l15, int lk, int ldst) {
  asm volatile("s_waitcnt vmcnt(%0)" :: "n"(VM) : "memory");
  __builtin_amdgcn_s_barrier();
  __builtin_amdgcn_sched_barrier(0);
  const int sw = l15 & 7;
  const int r0 = wm * 128 + (2 * P) * 16 + l15;
  const int r1 = r0 + 16;
  short8_t a00 = *(const short8_t*)(Ac + r0 * 64 + ((lk ^ sw) * 8));
  short8_t a01 = *(const short8_t*)(Ac + r0 * 64 + (((4 + lk) ^ sw) * 8));
  short8_t a10 = *(const short8_t*)(Ac + r1 * 64 + ((lk ^ sw) * 8));
  short8_t a11 = *(const short8_t*)(Ac + r1 * 64 + (((4 + lk) ^ sw) * 8));
  if (P == 0) {
#pragma unroll
    for (int nf = 0; nf < 4; ++nf) {
      const int rb = wn * 64 + nf * 16 + l15;  // rb&7 == sw
      bF[nf][0] = *(const short8_t*)(Bc + rb * 64 + ((lk ^ sw) * 8));
      bF[nf][1] = *(const short8_t*)(Bc + rb * 64 + (((4 + lk) ^ sw) * 8));
    }
  }
  if (STG) {
    if (P == 0) {
      gload_lds16(bsrc, Bn + ldst);
      gload_lds16(bsrc + 65536, Bn + 4096 + ldst);
    } else if (P == 1) {
      gload_lds16(bsrc + 2 * 65536, Bn + 2 * 4096 + ldst);
      gload_lds16(bsrc + 3 * 65536, Bn + 3 * 4096 + ldst);
    } else if (P == 2) {
      gload_lds16(asrc, An + ldst);
      gload_lds16(asrc + 65536, An + 4096 + ldst);
    } else {
      gload_lds16(asrc + 2 * 65536, An + 2 * 4096 + ldst);
      gload_lds16(asrc + 3 * 65536, An + 3 * 4096 + ldst);
    }
  }
  __builtin_amdgcn_s_setprio(1);
#pragma unroll
  for (int nf = 0; nf < 4; ++nf) {
    acc[2 * P][nf] = __builtin_amdgcn_mfma_f32_16x16x32_bf16(a00, bF[nf][0], acc[2 * P][nf], 0, 0, 0);
    acc[2 * P][nf] = __builtin_amdgcn_mfma_f32_16x16x32_bf16(a01, bF[nf][1], acc[2 * P][nf], 0, 0, 0);
    acc[2 * P + 1][nf] = __builtin_amdgcn_mfma_f32_16x16x32_bf16(a10, bF[nf][0], acc[2 * P + 1][nf], 0, 0, 0);
    acc[2 * P + 1][nf] = __builtin_amdgcn_mfma_f32_16x16x32_bf16(a11, bF[nf][1], acc[2 * P + 1][nf], 0, 0, 0);
  }
  __builtin_amdgcn_s_setprio(0);
}

// NOTE (R4): min-waves/EU = 1, NOT 2.  LDS (128 KiB) already caps occupancy at
// 1 block/CU = 2 waves/EU; (512,2) capped the unified RF at 256 regs/wave and
// spilled ~4.5 KB/thread to scratch (R3: WRITE_SIZE 1.18e6 KB).  (512,1) lifts
// the cap to 512 with zero occupancy cost.
__global__ __launch_bounds__(512, 1) void gemm_alpha_8p(
    const uint16_t* __restrict__ x_hi, const uint16_t* __restrict__ x_lo,
    const uint16_t* __restrict__ w_hiT, const uint16_t* __restrict__ w_loT,
    const float* __restrict__ b1, const float* __restrict__ w2,
    float* __restrict__ partial) {
  __shared__ uint16_t S[65536];  // 128 KiB: A0 @0, A1 @16384, B0 @32768, B1 @49152

  // XCD-aware mapping: each XCD gets 16 row-panels; 4 col-tiles of a row adjacent
  const int hw = blockIdx.x;
  const int slot = hw >> 3;
  const int rt = (hw & 7) * 16 + (slot >> 2);
  const int ct = slot & 3;
  const int rs0 = rt * 256;
  const int h0 = ct * 256;

  const int tid = threadIdx.x;
  const int lane = tid & 63;
  const int w = tid >> 6;
  const int wm = w >> 2, wn = w & 3;
  const int l15 = lane & 15, lk = lane >> 4;

  // staging per-thread geometry: one gload_lds16 per wave covers 8 rows x 128B
  const int srow = w * 8 + (lane >> 3);
  const int slotx = ((lane & 7) ^ ((lane >> 3) & 7)) * 8;  // pre-swizzled source col
  const size_t aoff = (size_t)(rs0 + srow) * C_DIM + slotx;
  const size_t boff = (size_t)(h0 + srow) * C_DIM + slotx;
  const int ldst = w * 512;  // wave-uniform elem offset within a quarter slab

  f32x4 acc[8][4];
#pragma unroll
  for (int i = 0; i < 8; ++i)
#pragma unroll
    for (int j = 0; j < 4; ++j) acc[i][j] = (f32x4){0.f, 0.f, 0.f, 0.f};
  short8_t bF[4][2];

  // prologue: stage tile 0 into buf 0, order B0..B3, A0..A3
  {
    const uint16_t* b0 = w_hiT + boff;
    const uint16_t* a0 = x_hi + aoff;
#pragma unroll
    for (int q = 0; q < 4; ++q) gload_lds16(b0 + q * 65536, S + 32768 + q * 4096 + ldst);
#pragma unroll
    for (int q = 0; q < 4; ++q) gload_lds16(a0 + q * 65536, S + q * 4096 + ldst);
  }

#pragma unroll 2
  for (int t = 0; t < NT; ++t) {
    const int c = t & 1;
    const uint16_t* Ac = S + c * 16384;
    const uint16_t* Bc = S + 32768 + c * 16384;
    uint16_t* An = S + (1 - c) * 16384;
    uint16_t* Bn = S + 32768 + (1 - c) * 16384;
    const int t1 = t + 1;
    const int th1 = t1 >> 4;  // K' third: 0=hi*hi 1=lo*hi 2=hi*lo
    const uint16_t* asrc = ((th1 == 1) ? x_lo : x_hi) + aoff + (size_t)(t1 & 15) * 64;
    const uint16_t* bsrc = ((th1 == 2) ? w_loT : w_hiT) + boff + (size_t)(t1 & 15) * 64;
    if (t1 < NT) {
      phase_body<0, true, 1>(Ac, Bc, asrc, bsrc, An, Bn, acc, bF, wm, wn, l15, lk, ldst);
      phase_body<1, true, 3>(Ac, Bc, asrc, bsrc, An, Bn, acc, bF, wm, wn, l15, lk, ldst);
      phase_body<2, true, 4>(Ac, Bc, asrc, bsrc, An, Bn, acc, bF, wm, wn, l15, lk, ldst);
      phase_body<3, true, 6>(Ac, Bc, asrc, bsrc, An, Bn, acc, bF, wm, wn, l15, lk, ldst);
    } else {
      phase_body<0, false, 1>(Ac, Bc, asrc, bsrc, An, Bn, acc, bF, wm, wn, l15, lk, ldst);
      phase_body<1, false, 1>(Ac, Bc, asrc, bsrc, An, Bn, acc, bF, wm, wn, l15, lk, ldst);
      phase_body<2, false, 0>(Ac, Bc, asrc, bsrc, An, Bn, acc, bF, wm, wn, l15, lk, ldst);
      phase_body<3, false, 0>(Ac, Bc, asrc, bsrc, An, Bn, acc, bF, wm, wn, l15, lk, ldst);
    }
  }

  // ---- epilogue: tanh + dot(w2) -> per-row partial ----
  __syncthreads();
  float* red = (float*)S;  // [256][65] = 66.5 KB
  float bv[4], wv[4];
#pragma unroll
  for (int nf = 0; nf < 4; ++nf) {
    const int h = h0 + wn * 64 + nf * 16 + l15;
    bv[nf] = b1[h];
    wv[nf] = w2[h];
  }
#pragma unroll
  for (int mf = 0; mf < 8; ++mf)
#pragma unroll
    for (int r = 0; r < 4; ++r) {
      float s = 0.f;
#pragma unroll
      for (int nf = 0; nf < 4; ++nf) s += tanh_fast(acc[mf][nf][r] + bv[nf]) * wv[nf];
      const int row = wm * 128 + mf * 16 + lk * 4 + r;
      red[row * 65 + wn * 16 + l15] = s;
    }
  __syncthreads();
  if (tid < 256) {
    float s = 0.f;
#pragma unroll
    for (int i = 0; i < 64; ++i) s += red[tid * 65 + i];
    partial[(size_t)ct * NROWS + rs0 + tid] = s;
  }
}

// ---------------- per-batch: alpha, alpha_sum, scale, cumsum, right_idx ----------------
__global__ __launch_bounds__(256) void scan_kernel(
    const float* __restrict__ partial, const int* __restrict__ tlen,
    const float* __restrict__ b2p,
    float* __restrict__ alpha_s, float* __restrict__ csum,
    int* __restrict__ ridx, float* __restrict__ tail) {
  const int b = blockIdx.x;
  const int tid = threadIdx.x;
  const float b2 = b2p[0];
  float a[8];
  float lsum = 0.f;
#pragma unroll
  for (int i = 0; i < 8; ++i) {
    int s = tid * 8 + i;
    float lg = b2;
#pragma unroll
    for (int t = 0; t < PT; ++t) lg += partial[t * NROWS + s * B_N + b];
    float al = 1.f / (1.f + expf(-lg));
    a[i] = al;
    lsum += al;
  }
  __shared__ float tsum[256];
  tsum[tid] = lsum;
  __syncthreads();
  for (int off = 1; off < 256; off <<= 1) {
    float v = 0.f;
    if (tid >= off) v = tsum[tid - off];
    __syncthreads();
    tsum[tid] += v;
    __syncthreads();
  }
  float total = tsum[255];
  float pre = tid ? tsum[tid - 1] : 0.f;
  float desired = (float)tlen[b] + 0.0001f; // BETA = 1
  float scale = desired / total;
  float run = pre;
#pragma unroll
  for (int i = 0; i < 8; ++i) {
    int s = tid * 8 + i;
    run += a[i];
    float cs = run * scale;
    int r = (int)floorf(cs);
    r = r < 0 ? 0 : (r > T_OUT ? T_OUT : r);
    alpha_s[b * S_LEN + s] = a[i] * scale;
    csum[b * S_LEN + s] = cs;
    ridx[b * S_LEN + s] = r;
  }
  if (tid == 0) {
    tail[b] = (float)tlen[b];       // feat_lengths (compared as float)
    tail[B_N + b] = total;          // alpha_sum (pre-scaling)
  }
}

// ---------------- per-(frame, batch): gather the contiguous s-band ----------------
__global__ __launch_bounds__(256) void frames_kernel(
    const float* __restrict__ x, const float* __restrict__ alpha_s,
    const float* __restrict__ csum, const int* __restrict__ ridx,
    float* __restrict__ out) {
  const int j = blockIdx.x;
  const int b = blockIdx.y;
  const int* r = ridx + b * S_LEN;
  const float* cs = csum + b * S_LEN;
  const float* as = alpha_s + b * S_LEN;

  int lo = 0, hi = S_LEN;
  while (lo < hi) { int m = (lo + hi) >> 1; if (r[m] < j) lo = m + 1; else hi = m; }
  const int sA = lo;
  hi = S_LEN;
  while (lo < hi) { int m = (lo + hi) >> 1; if (r[m] < j + 1) lo = m + 1; else hi = m; }
  int sEnd = lo;
  if (sEnd > S_LEN - 1) sEnd = S_LEN - 1;

  const int tid = threadIdx.x;
  float4 acc = make_float4(0.f, 0.f, 0.f, 0.f);
  for (int s = sA; s <= sEnd; ++s) {
    const int rr = r[s];
    const int l = s ? r[s - 1] : 0;
    float w = 0.f;
    if (rr == l) {
      if (j == rr) w = as[s];
    } else {
      float rw = cs[s] - (float)rr;
      if (j == rr) w = rw;
      else if (j == l) w = as[s] - rw - (float)(rr - l - 1);
      else w = 1.0f;
    }
    if (w != 0.f) {
      const float4 xv = *(const float4*)(x + ((size_t)s * B_N + b) * C_DIM + tid * 4);
      acc.x += w * xv.x; acc.y += w * xv.y; acc.z += w * xv.z; acc.w += w * xv.w;
    }
  }
  *(float4*)(out + ((size_t)j * B_N + b) * C_DIM + tid * 4) = acc;
}

extern "C" void kernel_launch(void* const* d_in, const int* in_sizes, int n_in,
                              void* d_out, int out_size, void* d_ws, size_t ws_size,
                              hipStream_t stream) {
  const float* x = (const float*)d_in[0];
  const int* tlen = (const int*)d_in[2];
  const float* w1 = (const float*)d_in[3];
  const float* b1 = (const float*)d_in[4];
  const float* v2 = (const float*)d_in[5];
  const float* g2 = (const float*)d_in[6];
  const float* b2 = (const float*)d_in[7];
  float* out = (float*)d_out;

  char* ws = (char*)d_ws;
  float* partial = (float*)ws;                          ws += sizeof(float) * PT * NROWS;
  float* alpha_s = (float*)ws;                          ws += sizeof(float) * NROWS;
  float* csum = (float*)ws;                             ws += sizeof(float) * NROWS;
  float* w2 = (float*)ws;                               ws += sizeof(float) * H_DIM;
  int* ridx = (int*)ws;                                 ws += sizeof(int) * NROWS;
  uint16_t* w_hiT = (uint16_t*)ws;                      ws += sizeof(uint16_t) * H_DIM * C_DIM;
  uint16_t* w_loT = (uint16_t*)ws;                      ws += sizeof(uint16_t) * H_DIM * C_DIM;
  uint16_t* x_hi = (uint16_t*)ws;                       ws += sizeof(uint16_t) * (size_t)NROWS * C_DIM;
  uint16_t* x_lo = (uint16_t*)ws;                       ws += sizeof(uint16_t) * (size_t)NROWS * C_DIM;

  w2_kernel<<<dim3(1), dim3(256), 0, stream>>>(v2, g2, w2);
  cvt_w_kernel<<<dim3(16, 16), dim3(256), 0, stream>>>(w1, w_hiT, w_loT);
  cvt_x_kernel<<<dim3(4096), dim3(256), 0, stream>>>(x, x_hi, x_lo);
  gemm_alpha_8p<<<dim3(512), dim3(512), 0, stream>>>(x_hi, x_lo, w_hiT, w_loT, b1, w2, partial);
  scan_kernel<<<dim3(B_N), dim3(256), 0, stream>>>(partial, tlen, b2, alpha_s, csum, ridx,
                                                   out + (size_t)T_OUT * B_N * C_DIM);
  frames_kernel<<<dim3(T_OUT, B_N), dim3(256), 0, stream>>>(x, alpha_s, csum, ridx, out);
}

// Round 6
// 639.857 us; speedup vs baseline: 1.0292x; 1.0192x over previous
//
#include <hip/hip_runtime.h>
#include <math.h>
#include <stdint.h>

#define S_LEN 2048
#define B_N 16
#define C_DIM 1024
#define H_DIM 1024
#define T_OUT 512
#define NROWS (S_LEN * B_N) /* 32768 */
#define PT 4                /* partial tiles: H / 256 */
#define NT 48               /* K' = 3*1024 / 64 */

typedef __attribute__((ext_vector_type(8))) short short8_t;
typedef __attribute__((ext_vector_type(4))) float f32x4;

__device__ __forceinline__ unsigned short f2bf_rne(float f) {
  unsigned u = __float_as_uint(f);
  u += 0x7FFF + ((u >> 16) & 1);
  return (unsigned short)(u >> 16);
}
__device__ __forceinline__ float bf2f(unsigned short h) {
  return __uint_as_float(((unsigned)h) << 16);
}
__device__ __forceinline__ unsigned pack2(unsigned short a, unsigned short b) {
  return (unsigned)a | ((unsigned)b << 16);
}
__device__ __forceinline__ void gload_lds16(const void* g, void* l) {
  __builtin_amdgcn_global_load_lds((const __attribute__((address_space(1))) unsigned*)g,
                                   (__attribute__((address_space(3))) unsigned*)l, 16, 0, 0);
}
__device__ __forceinline__ void split8(const float* f, uint4& hv, uint4& lv) {
  unsigned short hi[8], lo[8];
#pragma unroll
  for (int i = 0; i < 8; ++i) {
    hi[i] = f2bf_rne(f[i]);
    lo[i] = f2bf_rne(f[i] - bf2f(hi[i]));
  }
  hv.x = pack2(hi[0], hi[1]); hv.y = pack2(hi[2], hi[3]);
  hv.z = pack2(hi[4], hi[5]); hv.w = pack2(hi[6], hi[7]);
  lv.x = pack2(lo[0], lo[1]); lv.y = pack2(lo[2], lo[3]);
  lv.z = pack2(lo[4], lo[5]); lv.w = pack2(lo[6], lo[7]);
}
__device__ __forceinline__ float tanh_fast(float v) {
  return 1.f - 2.f / (__expf(2.f * v) + 1.f);
}

// ---------------- w2 = g2 * v2 / ||v2|| ----------------
__global__ __launch_bounds__(256) void w2_kernel(const float* __restrict__ v2,
                                                 const float* __restrict__ g2,
                                                 float* __restrict__ w2) {
  __shared__ float red[256];
  int tid = threadIdx.x;
  float s = 0.f;
  for (int h = tid; h < H_DIM; h += 256) { float v = v2[h]; s += v * v; }
  red[tid] = s;
  __syncthreads();
  for (int off = 128; off > 0; off >>= 1) {
    if (tid < off) red[tid] += red[tid + off];
    __syncthreads();
  }
  float scale = g2[0] / sqrtf(red[0]);
  for (int h = tid; h < H_DIM; h += 256) w2[h] = v2[h] * scale;
}

// ---------------- x -> x_hi, x_lo (bf16 split, once per element) ----------------
__global__ __launch_bounds__(256) void cvt_x_kernel(const float* __restrict__ x,
                                                    uint16_t* __restrict__ x_hi,
                                                    uint16_t* __restrict__ x_lo) {
  const size_t nchunks = (size_t)NROWS * C_DIM / 8;
  const size_t stride = (size_t)gridDim.x * blockDim.x;
  for (size_t i = (size_t)blockIdx.x * blockDim.x + threadIdx.x; i < nchunks; i += stride) {
    float4 v0 = *(const float4*)(x + i * 8);
    float4 v1 = *(const float4*)(x + i * 8 + 4);
    float f[8] = {v0.x, v0.y, v0.z, v0.w, v1.x, v1.y, v1.z, v1.w};
    uint4 hv, lv;
    split8(f, hv, lv);
    *(uint4*)(x_hi + i * 8) = hv;
    *(uint4*)(x_lo + i * 8) = lv;
  }
}

// ---------------- w1[c][h] -> w_hiT[h][c], w_loT[h][c] ----------------
__global__ __launch_bounds__(256) void cvt_w_kernel(const float* __restrict__ w1,
                                                    uint16_t* __restrict__ w_hiT,
                                                    uint16_t* __restrict__ w_loT) {
  __shared__ unsigned short hi_t[64][65], lo_t[64][65];
  const int h0 = blockIdx.x * 64, c0 = blockIdx.y * 64;
  const int tid = threadIdx.x;
  const int cl = tid >> 4;
  const int hl = (tid & 15) * 4;
#pragma unroll
  for (int k = 0; k < 4; ++k) {
    int c = cl + k * 16;
    float4 v = *(const float4*)(w1 + (size_t)(c0 + c) * H_DIM + h0 + hl);
    float f[4] = {v.x, v.y, v.z, v.w};
#pragma unroll
    for (int i = 0; i < 4; ++i) {
      unsigned short hi = f2bf_rne(f[i]);
      unsigned short lo = f2bf_rne(f[i] - bf2f(hi));
      hi_t[c][hl + i] = hi;
      lo_t[c][hl + i] = lo;
    }
  }
  __syncthreads();
  const int hr = tid >> 2;
  const int cc = (tid & 3) * 16;
  uint4 o[4];
#pragma unroll
  for (int g = 0; g < 2; ++g) {
    unsigned short (*src)[65] = g ? lo_t : hi_t;
    o[g * 2 + 0].x = pack2(src[cc + 0][hr], src[cc + 1][hr]);
    o[g * 2 + 0].y = pack2(src[cc + 2][hr], src[cc + 3][hr]);
    o[g * 2 + 0].z = pack2(src[cc + 4][hr], src[cc + 5][hr]);
    o[g * 2 + 0].w = pack2(src[cc + 6][hr], src[cc + 7][hr]);
    o[g * 2 + 1].x = pack2(src[cc + 8][hr], src[cc + 9][hr]);
    o[g * 2 + 1].y = pack2(src[cc + 10][hr], src[cc + 11][hr]);
    o[g * 2 + 1].z = pack2(src[cc + 12][hr], src[cc + 13][hr]);
    o[g * 2 + 1].w = pack2(src[cc + 14][hr], src[cc + 15][hr]);
  }
  uint16_t* ph = w_hiT + (size_t)(h0 + hr) * C_DIM + c0 + cc;
  uint16_t* pl = w_loT + (size_t)(h0 + hr) * C_DIM + c0 + cc;
  *(uint4*)ph = o[0]; *(uint4*)(ph + 8) = o[1];
  *(uint4*)pl = o[2]; *(uint4*)(pl + 8) = o[3];
}

// ---------------- 256x256x(K'=3072) phased bf16 GEMM + tanh/w2 epilogue -------
// Same schedule as R3/R4 (4 phases/K-tile, counted vmcnt {1,3,4,6}, both-sides
// XOR swizzle), but ALL phase code is macro-expanded in the kernel scope:
// no reference-passed arrays, no "memory" clobber -> acc/bF stay in registers
// (R3/R4 spilled ~4.5 KB/thread to scratch: WRITE_SIZE 1.18e6 KB).

#define MFMA4(P, NF, BF0, BF1)                                                              \
  acc[2*(P)][NF]   = __builtin_amdgcn_mfma_f32_16x16x32_bf16(a00, BF0, acc[2*(P)][NF], 0, 0, 0);   \
  acc[2*(P)][NF]   = __builtin_amdgcn_mfma_f32_16x16x32_bf16(a01, BF1, acc[2*(P)][NF], 0, 0, 0);   \
  acc[2*(P)+1][NF] = __builtin_amdgcn_mfma_f32_16x16x32_bf16(a10, BF0, acc[2*(P)+1][NF], 0, 0, 0); \
  acc[2*(P)+1][NF] = __builtin_amdgcn_mfma_f32_16x16x32_bf16(a11, BF1, acc[2*(P)+1][NF], 0, 0, 0);

#define LOAD_BF(NF, D0, D1) {                                             \
    const int rb_ = wn * 64 + (NF) * 16 + l15;                            \
    D0 = *(const short8_t*)(Bc + rb_ * 64 + ((lk ^ (l15 & 7)) * 8));      \
    D1 = *(const short8_t*)(Bc + rb_ * 64 + (((4 + lk) ^ (l15 & 7)) * 8));\
  }

#define PHASE(P, STG, VM) {                                                   \
    asm volatile("s_waitcnt vmcnt(" #VM ")");                                 \
    __builtin_amdgcn_sched_barrier(0);                                        \
    __builtin_amdgcn_s_barrier();                                             \
    __builtin_amdgcn_sched_barrier(0);                                        \
    const int r0_ = wm * 128 + (2 * (P)) * 16 + l15;                          \
    const int r1_ = r0_ + 16;                                                 \
    short8_t a00 = *(const short8_t*)(Ac + r0_ * 64 + ((lk ^ (l15 & 7)) * 8));        \
    short8_t a01 = *(const short8_t*)(Ac + r0_ * 64 + (((4 + lk) ^ (l15 & 7)) * 8));  \
    short8_t a10 = *(const short8_t*)(Ac + r1_ * 64 + ((lk ^ (l15 & 7)) * 8));        \
    short8_t a11 = *(const short8_t*)(Ac + r1_ * 64 + (((4 + lk) ^ (l15 & 7)) * 8));  \
    if ((P) == 0) {                                                           \
      LOAD_BF(0, bF00, bF01) LOAD_BF(1, bF10, bF11)                           \
      LOAD_BF(2, bF20, bF21) LOAD_BF(3, bF30, bF31)                           \
    }                                                                         \
    if (STG) {                                                                \
      if ((P) == 0) {                                                         \
        gload_lds16(bsrc, Bn + ldst);                                         \
        gload_lds16(bsrc + 65536, Bn + 4096 + ldst);                          \
      } else if ((P) == 1) {                                                  \
        gload_lds16(bsrc + 2 * 65536, Bn + 2 * 4096 + ldst);                  \
        gload_lds16(bsrc + 3 * 65536, Bn + 3 * 4096 + ldst);                  \
      } else if ((P) == 2) {                                                  \
        gload_lds16(asrc, An + ldst);                                         \
        gload_lds16(asrc + 65536, An + 4096 + ldst);                          \
      } else {                                                                \
        gload_lds16(asrc + 2 * 65536, An + 2 * 4096 + ldst);                  \
        gload_lds16(asrc + 3 * 65536, An + 3 * 4096 + ldst);                  \
      }                                                                       \
    }                                                                         \
    __builtin_amdgcn_s_setprio(1);                                            \
    MFMA4(P, 0, bF00, bF01) MFMA4(P, 1, bF10, bF11)                           \
    MFMA4(P, 2, bF20, bF21) MFMA4(P, 3, bF30, bF31)                           \
    __builtin_amdgcn_s_setprio(0);                                            \
  }

__global__ __launch_bounds__(512, 1) void gemm_alpha_8p(
    const uint16_t* __restrict__ x_hi, const uint16_t* __restrict__ x_lo,
    const uint16_t* __restrict__ w_hiT, const uint16_t* __restrict__ w_loT,
    const float* __restrict__ b1, const float* __restrict__ w2,
    float* __restrict__ partial) {
  __shared__ uint16_t S[65536];  // 128 KiB: A0 @0, A1 @16384, B0 @32768, B1 @49152

  // XCD-aware mapping: each XCD gets 16 row-panels; 4 col-tiles of a row adjacent
  const int hw = blockIdx.x;
  const int slot = hw >> 3;
  const int rt = (hw & 7) * 16 + (slot >> 2);
  const int ct = slot & 3;
  const int rs0 = rt * 256;
  const int h0 = ct * 256;

  const int tid = threadIdx.x;
  const int lane = tid & 63;
  const int w = tid >> 6;
  const int wm = w >> 2, wn = w & 3;
  const int l15 = lane & 15, lk = lane >> 4;

  // staging: one gload_lds16 per wave covers 8 rows x 128B of a quarter-slab
  const int srow = w * 8 + (lane >> 3);
  const int slotx = ((lane & 7) ^ ((lane >> 3) & 7)) * 8;  // pre-swizzled source col
  const size_t aoff = (size_t)(rs0 + srow) * C_DIM + slotx;
  const size_t boff = (size_t)(h0 + srow) * C_DIM + slotx;
  const int ldst = w * 512;  // wave-uniform elem offset within a quarter slab

  f32x4 acc[8][4];
#pragma unroll
  for (int i = 0; i < 8; ++i)
#pragma unroll
    for (int j = 0; j < 4; ++j) acc[i][j] = (f32x4){0.f, 0.f, 0.f, 0.f};
  short8_t bF00, bF01, bF10, bF11, bF20, bF21, bF30, bF31;

  // prologue: stage tile 0 into buf 0, order B0..B3, A0..A3
  {
    const uint16_t* b0 = w_hiT + boff;
    const uint16_t* a0 = x_hi + aoff;
#pragma unroll
    for (int q = 0; q < 4; ++q) gload_lds16(b0 + q * 65536, S + 32768 + q * 4096 + ldst);
#pragma unroll
    for (int q = 0; q < 4; ++q) gload_lds16(a0 + q * 65536, S + q * 4096 + ldst);
  }

#pragma unroll 2
  for (int t = 0; t < NT; ++t) {
    const int c = t & 1;
    const uint16_t* Ac = S + c * 16384;
    const uint16_t* Bc = S + 32768 + c * 16384;
    uint16_t* An = S + (1 - c) * 16384;
    uint16_t* Bn = S + 32768 + (1 - c) * 16384;
    const int t1 = t + 1;
    const int th1 = t1 >> 4;  // K' third: 0=hi*hi 1=lo*hi 2=hi*lo
    const uint16_t* asrc = ((th1 == 1) ? x_lo : x_hi) + aoff + (size_t)(t1 & 15) * 64;
    const uint16_t* bsrc = ((th1 == 2) ? w_loT : w_hiT) + boff + (size_t)(t1 & 15) * 64;
    if (t1 < NT) {
      PHASE(0, 1, 1)
      PHASE(1, 1, 3)
      PHASE(2, 1, 4)
      PHASE(3, 1, 6)
    } else {
      PHASE(0, 0, 1)
      PHASE(1, 0, 1)
      PHASE(2, 0, 0)
      PHASE(3, 0, 0)
    }
  }

  // ---- epilogue: tanh + dot(w2) -> per-row partial ----
  __syncthreads();
  float* red = (float*)S;  // [256][65] = 66.5 KB
  float bv[4], wv[4];
#pragma unroll
  for (int nf = 0; nf < 4; ++nf) {
    const int h = h0 + wn * 64 + nf * 16 + l15;
    bv[nf] = b1[h];
    wv[nf] = w2[h];
  }
#pragma unroll
  for (int mf = 0; mf < 8; ++mf)
#pragma unroll
    for (int r = 0; r < 4; ++r) {
      float s = 0.f;
#pragma unroll
      for (int nf = 0; nf < 4; ++nf) s += tanh_fast(acc[mf][nf][r] + bv[nf]) * wv[nf];
      const int row = wm * 128 + mf * 16 + lk * 4 + r;
      red[row * 65 + wn * 16 + l15] = s;
    }
  __syncthreads();
  if (tid < 256) {
    float s = 0.f;
#pragma unroll
    for (int i = 0; i < 64; ++i) s += red[tid * 65 + i];
    partial[(size_t)ct * NROWS + rs0 + tid] = s;
  }
}

// ---------------- per-batch: alpha, alpha_sum, scale, cumsum, right_idx ----------------
__global__ __launch_bounds__(256) void scan_kernel(
    const float* __restrict__ partial, const int* __restrict__ tlen,
    const float* __restrict__ b2p,
    float* __restrict__ alpha_s, float* __restrict__ csum,
    int* __restrict__ ridx, float* __restrict__ tail) {
  const int b = blockIdx.x;
  const int tid = threadIdx.x;
  const float b2 = b2p[0];
  float a[8];
  float lsum = 0.f;
#pragma unroll
  for (int i = 0; i < 8; ++i) {
    int s = tid * 8 + i;
    float lg = b2;
#pragma unroll
    for (int t = 0; t < PT; ++t) lg += partial[t * NROWS + s * B_N + b];
    float al = 1.f / (1.f + expf(-lg));
    a[i] = al;
    lsum += al;
  }
  __shared__ float tsum[256];
  tsum[tid] = lsum;
  __syncthreads();
  for (int off = 1; off < 256; off <<= 1) {
    float v = 0.f;
    if (tid >= off) v = tsum[tid - off];
    __syncthreads();
    tsum[tid] += v;
    __syncthreads();
  }
  float total = tsum[255];
  float pre = tid ? tsum[tid - 1] : 0.f;
  float desired = (float)tlen[b] + 0.0001f; // BETA = 1
  float scale = desired / total;
  float run = pre;
#pragma unroll
  for (int i = 0; i < 8; ++i) {
    int s = tid * 8 + i;
    run += a[i];
    float cs = run * scale;
    int r = (int)floorf(cs);
    r = r < 0 ? 0 : (r > T_OUT ? T_OUT : r);
    alpha_s[b * S_LEN + s] = a[i] * scale;
    csum[b * S_LEN + s] = cs;
    ridx[b * S_LEN + s] = r;
  }
  if (tid == 0) {
    tail[b] = (float)tlen[b];       // feat_lengths (compared as float)
    tail[B_N + b] = total;          // alpha_sum (pre-scaling)
  }
}

// ---------------- per-(frame, batch): gather the contiguous s-band ----------------
__global__ __launch_bounds__(256) void frames_kernel(
    const float* __restrict__ x, const float* __restrict__ alpha_s,
    const float* __restrict__ csum, const int* __restrict__ ridx,
    float* __restrict__ out) {
  const int j = blockIdx.x;
  const int b = blockIdx.y;
  const int* r = ridx + b * S_LEN;
  const float* cs = csum + b * S_LEN;
  const float* as = alpha_s + b * S_LEN;

  int lo = 0, hi = S_LEN;
  while (lo < hi) { int m = (lo + hi) >> 1; if (r[m] < j) lo = m + 1; else hi = m; }
  const int sA = lo;
  hi = S_LEN;
  while (lo < hi) { int m = (lo + hi) >> 1; if (r[m] < j + 1) lo = m + 1; else hi = m; }
  int sEnd = lo;
  if (sEnd > S_LEN - 1) sEnd = S_LEN - 1;

  const int tid = threadIdx.x;
  float4 acc = make_float4(0.f, 0.f, 0.f, 0.f);
  for (int s = sA; s <= sEnd; ++s) {
    const int rr = r[s];
    const int l = s ? r[s - 1] : 0;
    float w = 0.f;
    if (rr == l) {
      if (j == rr) w = as[s];
    } else {
      float rw = cs[s] - (float)rr;
      if (j == rr) w = rw;
      else if (j == l) w = as[s] - rw - (float)(rr - l - 1);
      else w = 1.0f;
    }
    if (w != 0.f) {
      const float4 xv = *(const float4*)(x + ((size_t)s * B_N + b) * C_DIM + tid * 4);
      acc.x += w * xv.x; acc.y += w * xv.y; acc.z += w * xv.z; acc.w += w * xv.w;
    }
  }
  *(float4*)(out + ((size_t)j * B_N + b) * C_DIM + tid * 4) = acc;
}

extern "C" void kernel_launch(void* const* d_in, const int* in_sizes, int n_in,
                              void* d_out, int out_size, void* d_ws, size_t ws_size,
                              hipStream_t stream) {
  const float* x = (const float*)d_in[0];
  const int* tlen = (const int*)d_in[2];
  const float* w1 = (const float*)d_in[3];
  const float* b1 = (const float*)d_in[4];
  const float* v2 = (const float*)d_in[5];
  const float* g2 = (const float*)d_in[6];
  const float* b2 = (const float*)d_in[7];
  float* out = (float*)d_out;

  char* ws = (char*)d_ws;
  float* partial = (float*)ws;                          ws += sizeof(float) * PT * NROWS;
  float* alpha_s = (float*)ws;                          ws += sizeof(float) * NROWS;
  float* csum = (float*)ws;                             ws += sizeof(float) * NROWS;
  float* w2 = (float*)ws;                               ws += sizeof(float) * H_DIM;
  int* ridx = (int*)ws;                                 ws += sizeof(int) * NROWS;
  uint16_t* w_hiT = (uint16_t*)ws;                      ws += sizeof(uint16_t) * H_DIM * C_DIM;
  uint16_t* w_loT = (uint16_t*)ws;                      ws += sizeof(uint16_t) * H_DIM * C_DIM;
  uint16_t* x_hi = (uint16_t*)ws;                       ws += sizeof(uint16_t) * (size_t)NROWS * C_DIM;
  uint16_t* x_lo = (uint16_t*)ws;                       ws += sizeof(uint16_t) * (size_t)NROWS * C_DIM;

  w2_kernel<<<dim3(1), dim3(256), 0, stream>>>(v2, g2, w2);
  cvt_w_kernel<<<dim3(16, 16), dim3(256), 0, stream>>>(w1, w_hiT, w_loT);
  cvt_x_kernel<<<dim3(4096), dim3(256), 0, stream>>>(x, x_hi, x_lo);
  gemm_alpha_8p<<<dim3(512), dim3(512), 0, stream>>>(x_hi, x_lo, w_hiT, w_loT, b1, w2, partial);
  scan_kernel<<<dim3(B_N), dim3(256), 0, stream>>>(partial, tlen, b2, alpha_s, csum, ridx,
                                                   out + (size_t)T_OUT * B_N * C_DIM);
  frames_kernel<<<dim3(T_OUT, B_N), dim3(256), 0, stream>>>(x, alpha_s, csum, ridx, out);
}

// Round 7
// 316.088 us; speedup vs baseline: 2.0834x; 2.0243x over previous
//
#include <hip/hip_runtime.h>
#include <math.h>
#include <stdint.h>

#define S_LEN 2048
#define B_N 16
#define C_DIM 1024
#define H_DIM 1024
#define T_OUT 512
#define NROWS (S_LEN * B_N) /* 32768 */
#define PT 4                /* partial tiles: H / 256 */
#define NT 48               /* K' = 3*1024 / 64 */

typedef __attribute__((ext_vector_type(8))) short short8_t;
typedef __attribute__((ext_vector_type(4))) float f32x4;

__device__ __forceinline__ unsigned short f2bf_rne(float f) {
  unsigned u = __float_as_uint(f);
  u += 0x7FFF + ((u >> 16) & 1);
  return (unsigned short)(u >> 16);
}
__device__ __forceinline__ float bf2f(unsigned short h) {
  return __uint_as_float(((unsigned)h) << 16);
}
__device__ __forceinline__ unsigned pack2(unsigned short a, unsigned short b) {
  return (unsigned)a | ((unsigned)b << 16);
}
__device__ __forceinline__ void gload_lds16(const void* g, void* l) {
  __builtin_amdgcn_global_load_lds((const __attribute__((address_space(1))) unsigned*)g,
                                   (__attribute__((address_space(3))) unsigned*)l, 16, 0, 0);
}
__device__ __forceinline__ void split8(const float* f, uint4& hv, uint4& lv) {
  unsigned short hi[8], lo[8];
#pragma unroll
  for (int i = 0; i < 8; ++i) {
    hi[i] = f2bf_rne(f[i]);
    lo[i] = f2bf_rne(f[i] - bf2f(hi[i]));
  }
  hv.x = pack2(hi[0], hi[1]); hv.y = pack2(hi[2], hi[3]);
  hv.z = pack2(hi[4], hi[5]); hv.w = pack2(hi[6], hi[7]);
  lv.x = pack2(lo[0], lo[1]); lv.y = pack2(lo[2], lo[3]);
  lv.z = pack2(lo[4], lo[5]); lv.w = pack2(lo[6], lo[7]);
}
__device__ __forceinline__ float tanh_fast(float v) {
  return 1.f - 2.f / (__expf(2.f * v) + 1.f);
}

// ---------------- w2 = g2 * v2 / ||v2|| ----------------
__global__ __launch_bounds__(256) void w2_kernel(const float* __restrict__ v2,
                                                 const float* __restrict__ g2,
                                                 float* __restrict__ w2) {
  __shared__ float red[256];
  int tid = threadIdx.x;
  float s = 0.f;
  for (int h = tid; h < H_DIM; h += 256) { float v = v2[h]; s += v * v; }
  red[tid] = s;
  __syncthreads();
  for (int off = 128; off > 0; off >>= 1) {
    if (tid < off) red[tid] += red[tid + off];
    __syncthreads();
  }
  float scale = g2[0] / sqrtf(red[0]);
  for (int h = tid; h < H_DIM; h += 256) w2[h] = v2[h] * scale;
}

// ---------------- x -> x_hi, x_lo (bf16 split, once per element) ----------------
__global__ __launch_bounds__(256) void cvt_x_kernel(const float* __restrict__ x,
                                                    uint16_t* __restrict__ x_hi,
                                                    uint16_t* __restrict__ x_lo) {
  const size_t nchunks = (size_t)NROWS * C_DIM / 8;
  const size_t stride = (size_t)gridDim.x * blockDim.x;
  for (size_t i = (size_t)blockIdx.x * blockDim.x + threadIdx.x; i < nchunks; i += stride) {
    float4 v0 = *(const float4*)(x + i * 8);
    float4 v1 = *(const float4*)(x + i * 8 + 4);
    float f[8] = {v0.x, v0.y, v0.z, v0.w, v1.x, v1.y, v1.z, v1.w};
    uint4 hv, lv;
    split8(f, hv, lv);
    *(uint4*)(x_hi + i * 8) = hv;
    *(uint4*)(x_lo + i * 8) = lv;
  }
}

// ---------------- w1[c][h] -> w_hiT[h][c], w_loT[h][c] ----------------
__global__ __launch_bounds__(256) void cvt_w_kernel(const float* __restrict__ w1,
                                                    uint16_t* __restrict__ w_hiT,
                                                    uint16_t* __restrict__ w_loT) {
  __shared__ unsigned short hi_t[64][65], lo_t[64][65];
  const int h0 = blockIdx.x * 64, c0 = blockIdx.y * 64;
  const int tid = threadIdx.x;
  const int cl = tid >> 4;
  const int hl = (tid & 15) * 4;
#pragma unroll
  for (int k = 0; k < 4; ++k) {
    int c = cl + k * 16;
    float4 v = *(const float4*)(w1 + (size_t)(c0 + c) * H_DIM + h0 + hl);
    float f[4] = {v.x, v.y, v.z, v.w};
#pragma unroll
    for (int i = 0; i < 4; ++i) {
      unsigned short hi = f2bf_rne(f[i]);
      unsigned short lo = f2bf_rne(f[i] - bf2f(hi));
      hi_t[c][hl + i] = hi;
      lo_t[c][hl + i] = lo;
    }
  }
  __syncthreads();
  const int hr = tid >> 2;
  const int cc = (tid & 3) * 16;
  uint4 o[4];
#pragma unroll
  for (int g = 0; g < 2; ++g) {
    unsigned short (*src)[65] = g ? lo_t : hi_t;
    o[g * 2 + 0].x = pack2(src[cc + 0][hr], src[cc + 1][hr]);
    o[g * 2 + 0].y = pack2(src[cc + 2][hr], src[cc + 3][hr]);
    o[g * 2 + 0].z = pack2(src[cc + 4][hr], src[cc + 5][hr]);
    o[g * 2 + 0].w = pack2(src[cc + 6][hr], src[cc + 7][hr]);
    o[g * 2 + 1].x = pack2(src[cc + 8][hr], src[cc + 9][hr]);
    o[g * 2 + 1].y = pack2(src[cc + 10][hr], src[cc + 11][hr]);
    o[g * 2 + 1].z = pack2(src[cc + 12][hr], src[cc + 13][hr]);
    o[g * 2 + 1].w = pack2(src[cc + 14][hr], src[cc + 15][hr]);
  }
  uint16_t* ph = w_hiT + (size_t)(h0 + hr) * C_DIM + c0 + cc;
  uint16_t* pl = w_loT + (size_t)(h0 + hr) * C_DIM + c0 + cc;
  *(uint4*)ph = o[0]; *(uint4*)(ph + 8) = o[1];
  *(uint4*)pl = o[2]; *(uint4*)(pl + 8) = o[3];
}

// ---------------- 256x256x(K'=3072) phased bf16 GEMM + tanh/w2 epilogue -------
// R6: all LDS addressing = 4 persistent 32-bit VGPRs + compile-time offset imms
// (buffer C and phase P are literal macro params); global staging = SGPR base +
// 32-bit lane offset.  Goal: total live regs < 256 (the HARD cap for an 8-wave
// block: 8 waves x R <= 4 SIMDs x 512) -> no scratch spill.
// LDS byte map: Abuf C @ C*32768, Bbuf C @ 65536 + C*32768 (65536 baked into bA*).
// Row = 128 B; slot swizzle: phys = logical ^ (row&7); k-half1 addr = addr ^ 64.

#define LDS_RD(A, IMM) (*(const short8_t*)(Sb + (A) + (IMM)))

#define MFMA4(P, NF, BF0, BF1)                                                                     \
  acc[2*(P)][NF]   = __builtin_amdgcn_mfma_f32_16x16x32_bf16(a00, BF0, acc[2*(P)][NF], 0, 0, 0);   \
  acc[2*(P)][NF]   = __builtin_amdgcn_mfma_f32_16x16x32_bf16(a01, BF1, acc[2*(P)][NF], 0, 0, 0);   \
  acc[2*(P)+1][NF] = __builtin_amdgcn_mfma_f32_16x16x32_bf16(a10, BF0, acc[2*(P)+1][NF], 0, 0, 0); \
  acc[2*(P)+1][NF] = __builtin_amdgcn_mfma_f32_16x16x32_bf16(a11, BF1, acc[2*(P)+1][NF], 0, 0, 0);

#define PH(P, C, VM, STG_STMTS) {                                             \
    asm volatile("s_waitcnt vmcnt(" #VM ")");                                 \
    __builtin_amdgcn_s_barrier();                                             \
    __builtin_amdgcn_sched_barrier(0);                                        \
    short8_t a00 = LDS_RD(aA0, (C)*32768 + (P)*4096);                         \
    short8_t a01 = LDS_RD(aA1, (C)*32768 + (P)*4096);                         \
    short8_t a10 = LDS_RD(aA0, (C)*32768 + (P)*4096 + 2048);                  \
    short8_t a11 = LDS_RD(aA1, (C)*32768 + (P)*4096 + 2048);                  \
    if ((P) == 0) {                                                           \
      bF00 = LDS_RD(bA0, (C)*32768 + 0);    bF01 = LDS_RD(bA1, (C)*32768 + 0);    \
      bF10 = LDS_RD(bA0, (C)*32768 + 2048); bF11 = LDS_RD(bA1, (C)*32768 + 2048); \
      bF20 = LDS_RD(bA0, (C)*32768 + 4096); bF21 = LDS_RD(bA1, (C)*32768 + 4096); \
      bF30 = LDS_RD(bA0, (C)*32768 + 6144); bF31 = LDS_RD(bA1, (C)*32768 + 6144); \
    }                                                                         \
    STG_STMTS                                                                 \
    __builtin_amdgcn_s_setprio(1);                                            \
    MFMA4(P, 0, bF00, bF01) MFMA4(P, 1, bF10, bF11)                           \
    MFMA4(P, 2, bF20, bF21) MFMA4(P, 3, bF30, bF31)                           \
    __builtin_amdgcn_s_setprio(0);                                            \
  }

#define BODY_STG(C, T1) {                                                     \
    const int th_ = (T1) >> 4;                                                \
    const uint16_t* as_ = ((th_ == 1) ? x_lo : x_hi) + (aoff32 + ((T1) & 15) * 64);   \
    const uint16_t* bs_ = ((th_ == 2) ? w_loT : w_hiT) + (boff32 + ((T1) & 15) * 64); \
    PH(0, C, 1, { gload_lds16(bs_,             S + 32768 + (1-(C))*16384 + 0    + wldst);   \
                  gload_lds16(bs_ + 65536,     S + 32768 + (1-(C))*16384 + 4096 + wldst); })\
    PH(1, C, 3, { gload_lds16(bs_ + 2*65536,   S + 32768 + (1-(C))*16384 + 8192 + wldst);   \
                  gload_lds16(bs_ + 3*65536,   S + 32768 + (1-(C))*16384 + 12288 + wldst); })\
    PH(2, C, 4, { gload_lds16(as_,             S + (1-(C))*16384 + 0    + wldst);           \
                  gload_lds16(as_ + 65536,     S + (1-(C))*16384 + 4096 + wldst); })        \
    PH(3, C, 6, { gload_lds16(as_ + 2*65536,   S + (1-(C))*16384 + 8192 + wldst);           \
                  gload_lds16(as_ + 3*65536,   S + (1-(C))*16384 + 12288 + wldst); })       \
  }

__global__ __launch_bounds__(512, 1) void gemm_alpha_8p(
    const uint16_t* __restrict__ x_hi, const uint16_t* __restrict__ x_lo,
    const uint16_t* __restrict__ w_hiT, const uint16_t* __restrict__ w_loT,
    const float* __restrict__ b1, const float* __restrict__ w2,
    float* __restrict__ partial) {
  __shared__ uint16_t S[65536];  // 128 KiB
  const char* Sb = (const char*)S;

  // XCD-aware mapping: each XCD gets 16 row-panels; 4 col-tiles of a row adjacent
  const int hw = blockIdx.x;
  const int slot = hw >> 3;
  const int rt = (hw & 7) * 16 + (slot >> 2);
  const int ct = slot & 3;
  const int rs0 = rt * 256;
  const int h0 = ct * 256;

  const int tid = threadIdx.x;
  const int lane = tid & 63;
  const int w = tid >> 6;
  const int wm = w >> 2, wn = w & 3;
  const int l15 = lane & 15, lk = lane >> 4;

  // persistent LDS read addresses (bytes): 4 VGPRs total
  const int aA0 = (wm * 128 + l15) * 128 + ((lk ^ (l15 & 7)) * 16);
  const int aA1 = aA0 ^ 64;                          // k-half 1 (slot ^ 4)
  const int bA0 = 65536 + (wn * 64 + l15) * 128 + ((lk ^ (l15 & 7)) * 16);
  const int bA1 = bA0 ^ 64;

  // staging: 32-bit per-lane global element offsets; SGPR bases added per body
  const int srow = w * 8 + (lane >> 3);
  const int slotx = ((lane & 7) ^ ((lane >> 3) & 7)) * 8;  // pre-swizzled source col
  const int aoff32 = (rs0 + srow) * C_DIM + slotx;
  const int boff32 = (h0 + srow) * C_DIM + slotx;
  const int wldst = __builtin_amdgcn_readfirstlane(w) * 512;  // wave-uniform LDS elem offset

  f32x4 acc[8][4];
#pragma unroll
  for (int i = 0; i < 8; ++i)
#pragma unroll
    for (int j = 0; j < 4; ++j) acc[i][j] = (f32x4){0.f, 0.f, 0.f, 0.f};
  short8_t bF00, bF01, bF10, bF11, bF20, bF21, bF30, bF31;

  // prologue: stage tile 0 into buf 0, order B0..B3, A0..A3 (matches ledger)
  {
    const uint16_t* as_ = x_hi + aoff32;
    const uint16_t* bs_ = w_hiT + boff32;
#pragma unroll
    for (int q = 0; q < 4; ++q) gload_lds16(bs_ + q * 65536, S + 32768 + q * 4096 + wldst);
#pragma unroll
    for (int q = 0; q < 4; ++q) gload_lds16(as_ + q * 65536, S + q * 4096 + wldst);
  }

#pragma unroll 1
  for (int u = 0; u < 23; ++u) {
    BODY_STG(0, 2 * u + 1)
    BODY_STG(1, 2 * u + 2)
  }
  BODY_STG(0, 47)
  // drain tile (t=47, buf 1, no staging): vmcnt {1,1,0,0}
  PH(0, 1, 1, {})
  PH(1, 1, 1, {})
  PH(2, 1, 0, {})
  PH(3, 1, 0, {})

  // ---- epilogue: tanh + dot(w2) -> per-row partial ----
  __syncthreads();
  float* red = (float*)S;  // [256][65] = 66.5 KB
  float bv[4], wv[4];
#pragma unroll
  for (int nf = 0; nf < 4; ++nf) {
    const int h = h0 + wn * 64 + nf * 16 + l15;
    bv[nf] = b1[h];
    wv[nf] = w2[h];
  }
#pragma unroll
  for (int mf = 0; mf < 8; ++mf)
#pragma unroll
    for (int r = 0; r < 4; ++r) {
      float s = 0.f;
#pragma unroll
      for (int nf = 0; nf < 4; ++nf) s += tanh_fast(acc[mf][nf][r] + bv[nf]) * wv[nf];
      const int row = wm * 128 + mf * 16 + lk * 4 + r;
      red[row * 65 + wn * 16 + l15] = s;
    }
  __syncthreads();
  if (tid < 256) {
    float s = 0.f;
#pragma unroll
    for (int i = 0; i < 64; ++i) s += red[tid * 65 + i];
    partial[(size_t)ct * NROWS + rs0 + tid] = s;
  }
}

// ---------------- per-batch: alpha, alpha_sum, scale, cumsum, right_idx ----------------
__global__ __launch_bounds__(256) void scan_kernel(
    const float* __restrict__ partial, const int* __restrict__ tlen,
    const float* __restrict__ b2p,
    float* __restrict__ alpha_s, float* __restrict__ csum,
    int* __restrict__ ridx, float* __restrict__ tail) {
  const int b = blockIdx.x;
  const int tid = threadIdx.x;
  const float b2 = b2p[0];
  float a[8];
  float lsum = 0.f;
#pragma unroll
  for (int i = 0; i < 8; ++i) {
    int s = tid * 8 + i;
    float lg = b2;
#pragma unroll
    for (int t = 0; t < PT; ++t) lg += partial[t * NROWS + s * B_N + b];
    float al = 1.f / (1.f + expf(-lg));
    a[i] = al;
    lsum += al;
  }
  __shared__ float tsum[256];
  tsum[tid] = lsum;
  __syncthreads();
  for (int off = 1; off < 256; off <<= 1) {
    float v = 0.f;
    if (tid >= off) v = tsum[tid - off];
    __syncthreads();
    tsum[tid] += v;
    __syncthreads();
  }
  float total = tsum[255];
  float pre = tid ? tsum[tid - 1] : 0.f;
  float desired = (float)tlen[b] + 0.0001f; // BETA = 1
  float scale = desired / total;
  float run = pre;
#pragma unroll
  for (int i = 0; i < 8; ++i) {
    int s = tid * 8 + i;
    run += a[i];
    float cs = run * scale;
    int r = (int)floorf(cs);
    r = r < 0 ? 0 : (r > T_OUT ? T_OUT : r);
    alpha_s[b * S_LEN + s] = a[i] * scale;
    csum[b * S_LEN + s] = cs;
    ridx[b * S_LEN + s] = r;
  }
  if (tid == 0) {
    tail[b] = (float)tlen[b];       // feat_lengths (compared as float)
    tail[B_N + b] = total;          // alpha_sum (pre-scaling)
  }
}

// ---------------- per-(frame, batch): gather the contiguous s-band ----------------
__global__ __launch_bounds__(256) void frames_kernel(
    const float* __restrict__ x, const float* __restrict__ alpha_s,
    const float* __restrict__ csum, const int* __restrict__ ridx,
    float* __restrict__ out) {
  const int j = blockIdx.x;
  const int b = blockIdx.y;
  const int* r = ridx + b * S_LEN;
  const float* cs = csum + b * S_LEN;
  const float* as = alpha_s + b * S_LEN;

  int lo = 0, hi = S_LEN;
  while (lo < hi) { int m = (lo + hi) >> 1; if (r[m] < j) lo = m + 1; else hi = m; }
  const int sA = lo;
  hi = S_LEN;
  while (lo < hi) { int m = (lo + hi) >> 1; if (r[m] < j + 1) lo = m + 1; else hi = m; }
  int sEnd = lo;
  if (sEnd > S_LEN - 1) sEnd = S_LEN - 1;

  const int tid = threadIdx.x;
  float4 acc = make_float4(0.f, 0.f, 0.f, 0.f);
  for (int s = sA; s <= sEnd; ++s) {
    const int rr = r[s];
    const int l = s ? r[s - 1] : 0;
    float w = 0.f;
    if (rr == l) {
      if (j == rr) w = as[s];
    } else {
      float rw = cs[s] - (float)rr;
      if (j == rr) w = rw;
      else if (j == l) w = as[s] - rw - (float)(rr - l - 1);
      else w = 1.0f;
    }
    if (w != 0.f) {
      const float4 xv = *(const float4*)(x + ((size_t)s * B_N + b) * C_DIM + tid * 4);
      acc.x += w * xv.x; acc.y += w * xv.y; acc.z += w * xv.z; acc.w += w * xv.w;
    }
  }
  *(float4*)(out + ((size_t)j * B_N + b) * C_DIM + tid * 4) = acc;
}

extern "C" void kernel_launch(void* const* d_in, const int* in_sizes, int n_in,
                              void* d_out, int out_size, void* d_ws, size_t ws_size,
                              hipStream_t stream) {
  const float* x = (const float*)d_in[0];
  const int* tlen = (const int*)d_in[2];
  const float* w1 = (const float*)d_in[3];
  const float* b1 = (const float*)d_in[4];
  const float* v2 = (const float*)d_in[5];
  const float* g2 = (const float*)d_in[6];
  const float* b2 = (const float*)d_in[7];
  float* out = (float*)d_out;

  char* ws = (char*)d_ws;
  float* partial = (float*)ws;                          ws += sizeof(float) * PT * NROWS;
  float* alpha_s = (float*)ws;                          ws += sizeof(float) * NROWS;
  float* csum = (float*)ws;                             ws += sizeof(float) * NROWS;
  float* w2 = (float*)ws;                               ws += sizeof(float) * H_DIM;
  int* ridx = (int*)ws;                                 ws += sizeof(int) * NROWS;
  uint16_t* w_hiT = (uint16_t*)ws;                      ws += sizeof(uint16_t) * H_DIM * C_DIM;
  uint16_t* w_loT = (uint16_t*)ws;                      ws += sizeof(uint16_t) * H_DIM * C_DIM;
  uint16_t* x_hi = (uint16_t*)ws;                       ws += sizeof(uint16_t) * (size_t)NROWS * C_DIM;
  uint16_t* x_lo = (uint16_t*)ws;                       ws += sizeof(uint16_t) * (size_t)NROWS * C_DIM;

  w2_kernel<<<dim3(1), dim3(256), 0, stream>>>(v2, g2, w2);
  cvt_w_kernel<<<dim3(16, 16), dim3(256), 0, stream>>>(w1, w_hiT, w_loT);
  cvt_x_kernel<<<dim3(4096), dim3(256), 0, stream>>>(x, x_hi, x_lo);
  gemm_alpha_8p<<<dim3(512), dim3(512), 0, stream>>>(x_hi, x_lo, w_hiT, w_loT, b1, w2, partial);
  scan_kernel<<<dim3(B_N), dim3(256), 0, stream>>>(partial, tlen, b2, alpha_s, csum, ridx,
                                                   out + (size_t)T_OUT * B_N * C_DIM);
  frames_kernel<<<dim3(T_OUT, B_N), dim3(256), 0, stream>>>(x, alpha_s, csum, ridx, out);
}

// Round 8
// 308.245 us; speedup vs baseline: 2.1364x; 1.0254x over previous
//
#include <hip/hip_runtime.h>
#include <math.h>
#include <stdint.h>

#define S_LEN 2048
#define B_N 16
#define C_DIM 1024
#define H_DIM 1024
#define T_OUT 512
#define NROWS (S_LEN * B_N) /* 32768 */
#define PT 4                /* partial tiles: H / 256 */
#define NT 48               /* K' = 3*1024 / 64 */

typedef __attribute__((ext_vector_type(8))) short short8_t;
typedef __attribute__((ext_vector_type(4))) float f32x4;

__device__ __forceinline__ unsigned short f2bf_rne(float f) {
  unsigned u = __float_as_uint(f);
  u += 0x7FFF + ((u >> 16) & 1);
  return (unsigned short)(u >> 16);
}
__device__ __forceinline__ float bf2f(unsigned short h) {
  return __uint_as_float(((unsigned)h) << 16);
}
__device__ __forceinline__ unsigned pack2(unsigned short a, unsigned short b) {
  return (unsigned)a | ((unsigned)b << 16);
}
__device__ __forceinline__ void gload_lds16(const void* g, void* l) {
  __builtin_amdgcn_global_load_lds((const __attribute__((address_space(1))) unsigned*)g,
                                   (__attribute__((address_space(3))) unsigned*)l, 16, 0, 0);
}
__device__ __forceinline__ void split8(const float* f, uint4& hv, uint4& lv) {
  unsigned short hi[8], lo[8];
#pragma unroll
  for (int i = 0; i < 8; ++i) {
    hi[i] = f2bf_rne(f[i]);
    lo[i] = f2bf_rne(f[i] - bf2f(hi[i]));
  }
  hv.x = pack2(hi[0], hi[1]); hv.y = pack2(hi[2], hi[3]);
  hv.z = pack2(hi[4], hi[5]); hv.w = pack2(hi[6], hi[7]);
  lv.x = pack2(lo[0], lo[1]); lv.y = pack2(lo[2], lo[3]);
  lv.z = pack2(lo[4], lo[5]); lv.w = pack2(lo[6], lo[7]);
}
__device__ __forceinline__ float tanh_fast(float v) {
  return 1.f - 2.f / (__expf(2.f * v) + 1.f);
}

// ---------------- w2 = g2 * v2 / ||v2|| ----------------
__global__ __launch_bounds__(256) void w2_kernel(const float* __restrict__ v2,
                                                 const float* __restrict__ g2,
                                                 float* __restrict__ w2) {
  __shared__ float red[256];
  int tid = threadIdx.x;
  float s = 0.f;
  for (int h = tid; h < H_DIM; h += 256) { float v = v2[h]; s += v * v; }
  red[tid] = s;
  __syncthreads();
  for (int off = 128; off > 0; off >>= 1) {
    if (tid < off) red[tid] += red[tid + off];
    __syncthreads();
  }
  float scale = g2[0] / sqrtf(red[0]);
  for (int h = tid; h < H_DIM; h += 256) w2[h] = v2[h] * scale;
}

// ---------------- x -> x_hi, x_lo (bf16 split, once per element) ----------------
__global__ __launch_bounds__(256) void cvt_x_kernel(const float* __restrict__ x,
                                                    uint16_t* __restrict__ x_hi,
                                                    uint16_t* __restrict__ x_lo) {
  const size_t nchunks = (size_t)NROWS * C_DIM / 8;
  const size_t stride = (size_t)gridDim.x * blockDim.x;
  for (size_t i = (size_t)blockIdx.x * blockDim.x + threadIdx.x; i < nchunks; i += stride) {
    float4 v0 = *(const float4*)(x + i * 8);
    float4 v1 = *(const float4*)(x + i * 8 + 4);
    float f[8] = {v0.x, v0.y, v0.z, v0.w, v1.x, v1.y, v1.z, v1.w};
    uint4 hv, lv;
    split8(f, hv, lv);
    *(uint4*)(x_hi + i * 8) = hv;
    *(uint4*)(x_lo + i * 8) = lv;
  }
}

// ---------------- w1[c][h] -> w_hiT[h][c], w_loT[h][c] ----------------
__global__ __launch_bounds__(256) void cvt_w_kernel(const float* __restrict__ w1,
                                                    uint16_t* __restrict__ w_hiT,
                                                    uint16_t* __restrict__ w_loT) {
  __shared__ unsigned short hi_t[64][65], lo_t[64][65];
  const int h0 = blockIdx.x * 64, c0 = blockIdx.y * 64;
  const int tid = threadIdx.x;
  const int cl = tid >> 4;
  const int hl = (tid & 15) * 4;
#pragma unroll
  for (int k = 0; k < 4; ++k) {
    int c = cl + k * 16;
    float4 v = *(const float4*)(w1 + (size_t)(c0 + c) * H_DIM + h0 + hl);
    float f[4] = {v.x, v.y, v.z, v.w};
#pragma unroll
    for (int i = 0; i < 4; ++i) {
      unsigned short hi = f2bf_rne(f[i]);
      unsigned short lo = f2bf_rne(f[i] - bf2f(hi));
      hi_t[c][hl + i] = hi;
      lo_t[c][hl + i] = lo;
    }
  }
  __syncthreads();
  const int hr = tid >> 2;
  const int cc = (tid & 3) * 16;
  uint4 o[4];
#pragma unroll
  for (int g = 0; g < 2; ++g) {
    unsigned short (*src)[65] = g ? lo_t : hi_t;
    o[g * 2 + 0].x = pack2(src[cc + 0][hr], src[cc + 1][hr]);
    o[g * 2 + 0].y = pack2(src[cc + 2][hr], src[cc + 3][hr]);
    o[g * 2 + 0].z = pack2(src[cc + 4][hr], src[cc + 5][hr]);
    o[g * 2 + 0].w = pack2(src[cc + 6][hr], src[cc + 7][hr]);
    o[g * 2 + 1].x = pack2(src[cc + 8][hr], src[cc + 9][hr]);
    o[g * 2 + 1].y = pack2(src[cc + 10][hr], src[cc + 11][hr]);
    o[g * 2 + 1].z = pack2(src[cc + 12][hr], src[cc + 13][hr]);
    o[g * 2 + 1].w = pack2(src[cc + 14][hr], src[cc + 15][hr]);
  }
  uint16_t* ph = w_hiT + (size_t)(h0 + hr) * C_DIM + c0 + cc;
  uint16_t* pl = w_loT + (size_t)(h0 + hr) * C_DIM + c0 + cc;
  *(uint4*)ph = o[0]; *(uint4*)(ph + 8) = o[1];
  *(uint4*)pl = o[2]; *(uint4*)(pl + 8) = o[3];
}

// ---------------- 256x256x(K'=3072) phased bf16 GEMM + tanh/w2 epilogue -------
// R7: A-fragment PREFETCH one phase ahead (m201 pattern) — phase P issues phase
// P+1's ds_reads before P's MFMA so LDS latency hides under the MFMA block.
// New stage order per tile: P0:{B0,B1} P1:{B2,B3} P2:{A-q0,A-q2} P3:{A-q1,A-q3};
// vmcnt {2,2,4,6} (drain {2,0,0,0}).  Verified: P0/P1-frag reads touch A-q0,q2
// (retired by vmcnt(2) at P0); P2/P3-frag reads touch A-q1,q3 (retired by
// vmcnt(2) at P1, before their issue point at P1/P2).  B fully retired at P0.
// Addressing: 4 persistent 32-bit byte addrs + literal offsets (R6, no spill).

#define LDSF(A, IMM) (*(const short8_t*)(Sb + (A) + (IMM)))

#define MM(P, NF, B0, B1, A00, A01, A10, A11)                                                        \
  acc[2*(P)][NF]   = __builtin_amdgcn_mfma_f32_16x16x32_bf16(A00, B0, acc[2*(P)][NF], 0, 0, 0);      \
  acc[2*(P)][NF]   = __builtin_amdgcn_mfma_f32_16x16x32_bf16(A01, B1, acc[2*(P)][NF], 0, 0, 0);      \
  acc[2*(P)+1][NF] = __builtin_amdgcn_mfma_f32_16x16x32_bf16(A10, B0, acc[2*(P)+1][NF], 0, 0, 0);    \
  acc[2*(P)+1][NF] = __builtin_amdgcn_mfma_f32_16x16x32_bf16(A11, B1, acc[2*(P)+1][NF], 0, 0, 0);

#define MFMA_PH(P, A00, A01, A10, A11)            \
  MM(P, 0, bF00, bF01, A00, A01, A10, A11)        \
  MM(P, 1, bF10, bF11, A00, A01, A10, A11)        \
  MM(P, 2, bF20, bF21, A00, A01, A10, A11)        \
  MM(P, 3, bF30, bF31, A00, A01, A10, A11)

#define SYNC(VM)                                  \
  __builtin_amdgcn_sched_barrier(0);              \
  asm volatile("s_waitcnt vmcnt(" #VM ")");       \
  __builtin_amdgcn_s_barrier();                   \
  __builtin_amdgcn_sched_barrier(0);

#define TILE(C, T1, STG, V0, V1, V2, V3) {                                        \
    const int th_ = (T1) >> 4;                                                    \
    const uint16_t* as_ = ((th_ == 1) ? x_lo : x_hi) + (aoff32 + ((T1) & 15) * 64);   \
    const uint16_t* bs_ = ((th_ == 2) ? w_loT : w_hiT) + (boff32 + ((T1) & 15) * 64); \
    /* ---- P0 ---- */                                                            \
    SYNC(V0)                                                                      \
    short8_t a00 = LDSF(aA0, (C)*32768 + 0);                                      \
    short8_t a01 = LDSF(aA1, (C)*32768 + 0);                                      \
    short8_t a10 = LDSF(aA0, (C)*32768 + 2048);                                   \
    short8_t a11 = LDSF(aA1, (C)*32768 + 2048);                                   \
    bF00 = LDSF(bA0, (C)*32768 + 0);    bF01 = LDSF(bA1, (C)*32768 + 0);          \
    bF10 = LDSF(bA0, (C)*32768 + 2048); bF11 = LDSF(bA1, (C)*32768 + 2048);       \
    bF20 = LDSF(bA0, (C)*32768 + 4096); bF21 = LDSF(bA1, (C)*32768 + 4096);       \
    bF30 = LDSF(bA0, (C)*32768 + 6144); bF31 = LDSF(bA1, (C)*32768 + 6144);       \
    short8_t p00 = LDSF(aA0, (C)*32768 + 4096);                                   \
    short8_t p01 = LDSF(aA1, (C)*32768 + 4096);                                   \
    short8_t p10 = LDSF(aA0, (C)*32768 + 6144);                                   \
    short8_t p11 = LDSF(aA1, (C)*32768 + 6144);                                   \
    if (STG) { gload_lds16(bs_,         S + 32768 + (1-(C))*16384 + 0    + wldst);\
               gload_lds16(bs_ + 65536, S + 32768 + (1-(C))*16384 + 4096 + wldst);}\
    __builtin_amdgcn_s_setprio(1);                                                \
    MFMA_PH(0, a00, a01, a10, a11)                                                \
    __builtin_amdgcn_s_setprio(0);                                                \
    /* ---- P1 (uses prefetched p; prefetches P2 into a) ---- */                  \
    SYNC(V1)                                                                      \
    a00 = LDSF(aA0, (C)*32768 + 8192);                                            \
    a01 = LDSF(aA1, (C)*32768 + 8192);                                            \
    a10 = LDSF(aA0, (C)*32768 + 10240);                                           \
    a11 = LDSF(aA1, (C)*32768 + 10240);                                           \
    if (STG) { gload_lds16(bs_ + 2*65536, S + 32768 + (1-(C))*16384 + 8192  + wldst);\
               gload_lds16(bs_ + 3*65536, S + 32768 + (1-(C))*16384 + 12288 + wldst);}\
    __builtin_amdgcn_s_setprio(1);                                                \
    MFMA_PH(1, p00, p01, p10, p11)                                                \
    __builtin_amdgcn_s_setprio(0);                                                \
    /* ---- P2 (uses a; prefetches P3 into p; stages A-q0,q2) ---- */             \
    SYNC(V2)                                                                      \
    p00 = LDSF(aA0, (C)*32768 + 12288);                                           \
    p01 = LDSF(aA1, (C)*32768 + 12288);                                           \
    p10 = LDSF(aA0, (C)*32768 + 14336);                                           \
    p11 = LDSF(aA1, (C)*32768 + 14336);                                           \
    if (STG) { gload_lds16(as_,           S + (1-(C))*16384 + 0    + wldst);      \
               gload_lds16(as_ + 2*65536, S + (1-(C))*16384 + 8192 + wldst); }    \
    __builtin_amdgcn_s_setprio(1);                                                \
    MFMA_PH(2, a00, a01, a10, a11)                                                \
    __builtin_amdgcn_s_setprio(0);                                                \
    /* ---- P3 (uses p; stages A-q1,q3) ---- */                                   \
    SYNC(V3)                                                                      \
    if (STG) { gload_lds16(as_ + 65536,   S + (1-(C))*16384 + 4096  + wldst);     \
               gload_lds16(as_ + 3*65536, S + (1-(C))*16384 + 12288 + wldst); }   \
    __builtin_amdgcn_s_setprio(1);                                                \
    MFMA_PH(3, p00, p01, p10, p11)                                                \
    __builtin_amdgcn_s_setprio(0);                                                \
  }

__global__ __launch_bounds__(512, 1) void gemm_alpha_8p(
    const uint16_t* __restrict__ x_hi, const uint16_t* __restrict__ x_lo,
    const uint16_t* __restrict__ w_hiT, const uint16_t* __restrict__ w_loT,
    const float* __restrict__ b1, const float* __restrict__ w2,
    float* __restrict__ partial) {
  __shared__ uint16_t S[65536];  // 128 KiB
  const char* Sb = (const char*)S;

  // XCD-aware mapping: each XCD gets 16 row-panels; 4 col-tiles of a row adjacent
  const int hw = blockIdx.x;
  const int slot = hw >> 3;
  const int rt = (hw & 7) * 16 + (slot >> 2);
  const int ct = slot & 3;
  const int rs0 = rt * 256;
  const int h0 = ct * 256;

  const int tid = threadIdx.x;
  const int lane = tid & 63;
  const int w = tid >> 6;
  const int wm = w >> 2, wn = w & 3;
  const int l15 = lane & 15, lk = lane >> 4;

  // persistent LDS read addresses (bytes)
  const int aA0 = (wm * 128 + l15) * 128 + ((lk ^ (l15 & 7)) * 16);
  const int aA1 = aA0 ^ 64;                          // k-half 1 (slot ^ 4)
  const int bA0 = 65536 + (wn * 64 + l15) * 128 + ((lk ^ (l15 & 7)) * 16);
  const int bA1 = bA0 ^ 64;

  // staging: 32-bit per-lane global element offsets
  const int srow = w * 8 + (lane >> 3);
  const int slotx = ((lane & 7) ^ ((lane >> 3) & 7)) * 8;  // pre-swizzled source col
  const int aoff32 = (rs0 + srow) * C_DIM + slotx;
  const int boff32 = (h0 + srow) * C_DIM + slotx;
  const int wldst = __builtin_amdgcn_readfirstlane(w) * 512;  // wave-uniform LDS elem offset

  f32x4 acc[8][4];
#pragma unroll
  for (int i = 0; i < 8; ++i)
#pragma unroll
    for (int j = 0; j < 4; ++j) acc[i][j] = (f32x4){0.f, 0.f, 0.f, 0.f};
  short8_t bF00, bF01, bF10, bF11, bF20, bF21, bF30, bF31;

  // prologue: stage tile 0 into buf 0; order [B0,B1,B2,B3, A-q0,A-q2, A-q1,A-q3]
  {
    const uint16_t* as_ = x_hi + aoff32;
    const uint16_t* bs_ = w_hiT + boff32;
#pragma unroll
    for (int q = 0; q < 4; ++q) gload_lds16(bs_ + q * 65536, S + 32768 + q * 4096 + wldst);
    gload_lds16(as_,             S + 0     + wldst);
    gload_lds16(as_ + 2 * 65536, S + 8192  + wldst);
    gload_lds16(as_ + 65536,     S + 4096  + wldst);
    gload_lds16(as_ + 3 * 65536, S + 12288 + wldst);
  }

#pragma unroll 1
  for (int u = 0; u < 23; ++u) {
    TILE(0, 2 * u + 1, 1, 2, 2, 4, 6)
    TILE(1, 2 * u + 2, 1, 2, 2, 4, 6)
  }
  TILE(0, 47, 1, 2, 2, 4, 6)
  // drain tile (buf 1, no staging)
  TILE(1, 48, 0, 2, 0, 0, 0)

  // ---- epilogue: tanh + dot(w2) -> per-row partial (transposed: [ct][b][s]) ----
  __syncthreads();
  float* red = (float*)S;  // [256][65] = 66.5 KB
  float bv[4], wv[4];
#pragma unroll
  for (int nf = 0; nf < 4; ++nf) {
    const int h = h0 + wn * 64 + nf * 16 + l15;
    bv[nf] = b1[h];
    wv[nf] = w2[h];
  }
#pragma unroll
  for (int mf = 0; mf < 8; ++mf)
#pragma unroll
    for (int r = 0; r < 4; ++r) {
      float s = 0.f;
#pragma unroll
      for (int nf = 0; nf < 4; ++nf) s += tanh_fast(acc[mf][nf][r] + bv[nf]) * wv[nf];
      const int row = wm * 128 + mf * 16 + lk * 4 + r;
      red[row * 65 + wn * 16 + l15] = s;
    }
  __syncthreads();
  if (tid < 256) {
    float s = 0.f;
#pragma unroll
    for (int i = 0; i < 64; ++i) s += red[tid * 65 + i];
    const int gr = rs0 + tid;
    partial[(size_t)ct * NROWS + (gr & 15) * S_LEN + (gr >> 4)] = s;
  }
}

// ---------------- per-batch: alpha, alpha_sum, scale, cumsum, right_idx ----------------
__global__ __launch_bounds__(256) void scan_kernel(
    const float* __restrict__ partial, const int* __restrict__ tlen,
    const float* __restrict__ b2p,
    float* __restrict__ alpha_s, float* __restrict__ csum,
    int* __restrict__ ridx, float* __restrict__ tail) {
  const int b = blockIdx.x;
  const int tid = threadIdx.x;
  const float b2 = b2p[0];
  float a[8];
  float lsum = 0.f;
#pragma unroll
  for (int i = 0; i < 8; ++i) {
    int s = tid * 8 + i;
    float lg = b2;
#pragma unroll
    for (int t = 0; t < PT; ++t) lg += partial[t * NROWS + b * S_LEN + s];
    float al = 1.f / (1.f + expf(-lg));
    a[i] = al;
    lsum += al;
  }
  __shared__ float tsum[256];
  tsum[tid] = lsum;
  __syncthreads();
  for (int off = 1; off < 256; off <<= 1) {
    float v = 0.f;
    if (tid >= off) v = tsum[tid - off];
    __syncthreads();
    tsum[tid] += v;
    __syncthreads();
  }
  float total = tsum[255];
  float pre = tid ? tsum[tid - 1] : 0.f;
  float desired = (float)tlen[b] + 0.0001f; // BETA = 1
  float scale = desired / total;
  float run = pre;
#pragma unroll
  for (int i = 0; i < 8; ++i) {
    int s = tid * 8 + i;
    run += a[i];
    float cs = run * scale;
    int r = (int)floorf(cs);
    r = r < 0 ? 0 : (r > T_OUT ? T_OUT : r);
    alpha_s[b * S_LEN + s] = a[i] * scale;
    csum[b * S_LEN + s] = cs;
    ridx[b * S_LEN + s] = r;
  }
  if (tid == 0) {
    tail[b] = (float)tlen[b];       // feat_lengths (compared as float)
    tail[B_N + b] = total;          // alpha_sum (pre-scaling)
  }
}

// ---------------- per-(frame, batch): gather the contiguous s-band ----------------
__global__ __launch_bounds__(256) void frames_kernel(
    const float* __restrict__ x, const float* __restrict__ alpha_s,
    const float* __restrict__ csum, const int* __restrict__ ridx,
    float* __restrict__ out) {
  const int j = blockIdx.x;
  const int b = blockIdx.y;
  const int* r = ridx + b * S_LEN;
  const float* cs = csum + b * S_LEN;
  const float* as = alpha_s + b * S_LEN;

  int lo = 0, hi = S_LEN;
  while (lo < hi) { int m = (lo + hi) >> 1; if (r[m] < j) lo = m + 1; else hi = m; }
  const int sA = lo;
  hi = S_LEN;
  while (lo < hi) { int m = (lo + hi) >> 1; if (r[m] < j + 1) lo = m + 1; else hi = m; }
  int sEnd = lo;
  if (sEnd > S_LEN - 1) sEnd = S_LEN - 1;

  const int tid = threadIdx.x;
  float4 acc = make_float4(0.f, 0.f, 0.f, 0.f);
  for (int s = sA; s <= sEnd; ++s) {
    const int rr = r[s];
    const int l = s ? r[s - 1] : 0;
    float w = 0.f;
    if (rr == l) {
      if (j == rr) w = as[s];
    } else {
      float rw = cs[s] - (float)rr;
      if (j == rr) w = rw;
      else if (j == l) w = as[s] - rw - (float)(rr - l - 1);
      else w = 1.0f;
    }
    if (w != 0.f) {
      const float4 xv = *(const float4*)(x + ((size_t)s * B_N + b) * C_DIM + tid * 4);
      acc.x += w * xv.x; acc.y += w * xv.y; acc.z += w * xv.z; acc.w += w * xv.w;
    }
  }
  *(float4*)(out + ((size_t)j * B_N + b) * C_DIM + tid * 4) = acc;
}

extern "C" void kernel_launch(void* const* d_in, const int* in_sizes, int n_in,
                              void* d_out, int out_size, void* d_ws, size_t ws_size,
                              hipStream_t stream) {
  const float* x = (const float*)d_in[0];
  const int* tlen = (const int*)d_in[2];
  const float* w1 = (const float*)d_in[3];
  const float* b1 = (const float*)d_in[4];
  const float* v2 = (const float*)d_in[5];
  const float* g2 = (const float*)d_in[6];
  const float* b2 = (const float*)d_in[7];
  float* out = (float*)d_out;

  char* ws = (char*)d_ws;
  float* partial = (float*)ws;                          ws += sizeof(float) * PT * NROWS;
  float* alpha_s = (float*)ws;                          ws += sizeof(float) * NROWS;
  float* csum = (float*)ws;                             ws += sizeof(float) * NROWS;
  float* w2 = (float*)ws;                               ws += sizeof(float) * H_DIM;
  int* ridx = (int*)ws;                                 ws += sizeof(int) * NROWS;
  uint16_t* w_hiT = (uint16_t*)ws;                      ws += sizeof(uint16_t) * H_DIM * C_DIM;
  uint16_t* w_loT = (uint16_t*)ws;                      ws += sizeof(uint16_t) * H_DIM * C_DIM;
  uint16_t* x_hi = (uint16_t*)ws;                       ws += sizeof(uint16_t) * (size_t)NROWS * C_DIM;
  uint16_t* x_lo = (uint16_t*)ws;                       ws += sizeof(uint16_t) * (size_t)NROWS * C_DIM;

  w2_kernel<<<dim3(1), dim3(256), 0, stream>>>(v2, g2, w2);
  cvt_w_kernel<<<dim3(16, 16), dim3(256), 0, stream>>>(w1, w_hiT, w_loT);
  cvt_x_kernel<<<dim3(4096), dim3(256), 0, stream>>>(x, x_hi, x_lo);
  gemm_alpha_8p<<<dim3(512), dim3(512), 0, stream>>>(x_hi, x_lo, w_hiT, w_loT, b1, w2, partial);
  scan_kernel<<<dim3(B_N), dim3(256), 0, stream>>>(partial, tlen, b2, alpha_s, csum, ridx,
                                                   out + (size_t)T_OUT * B_N * C_DIM);
  frames_kernel<<<dim3(T_OUT, B_N), dim3(256), 0, stream>>>(x, alpha_s, csum, ridx, out);
}